// Round 4
// baseline (93827.728 us; speedup 1.0000x reference)
//
#include <hip/hip_runtime.h>
#include <hip/hip_bf16.h>
#include <hip/hip_cooperative_groups.h>

namespace cg = cooperative_groups;

#define NB 64
#define NT 600
#define NTC 50
#define NH 400
#define NKATT 10
#define NALPHA 60
#define NOUT 121

typedef unsigned short u16;
typedef _Float16 f16x2 __attribute__((ext_vector_type(2)));
typedef _Float16 f16x4 __attribute__((ext_vector_type(4)));

#if defined(__has_builtin)
#if __has_builtin(__builtin_amdgcn_fdot2)
#define FDOT2(a,b,c) __builtin_amdgcn_fdot2((a),(b),(c),false)
#endif
#endif
#ifndef FDOT2
#define FDOT2(a,b,c) ((c) + (float)(a)[0]*(float)(b)[0] + (float)(a)[1]*(float)(b)[1])
#endif

// Padded fused-K sizes (pairs): K1=512->256, K2=896->448, K3=1280->640. Rows padded 1600->1664.
#define ROWSP 1664

// state layout (floats)
#define H1OFF 0            // [2][NB][NH] ping-pong
#define H2OFF 51200
#define H3OFF 102400
#define C1OFF 153600
#define C2OFF 179200
#define C3OFF 204800
#define KPOFF 230400       // [2][NB][NKATT]
#define WINOFF 231680      // [NB][NALPHA]
#define ST_FLOATS 235520

__device__ __align__(16) f16x2 g_WT1[256 * ROWSP];
__device__ __align__(16) f16x2 g_WT2[448 * ROWSP];
__device__ __align__(16) f16x2 g_WT3[640 * ROWSP];
__device__ __align__(16) f16x2 g_WG2[600 * 128];
__device__ __align__(16) float g_fb1[ROWSP], g_fb2[ROWSP], g_fb3[ROWSP];
__device__ __align__(16) float g_WattT[400 * 32];
__device__ float g_batt[30], g_bgmm[121];
__device__ __align__(16) float g_inp[115200];
__device__ float g_state[ST_FLOATS];
__device__ int   g_isf32;

__device__ __forceinline__ float bf2f(u16 v) {
    union { unsigned int u; float f; } t; t.u = ((unsigned int)v) << 16; return t.f;
}
__device__ __forceinline__ u16 f2bf(float f) {
    union { float ff; unsigned int u; } t; t.ff = f;
    unsigned int lsb = (t.u >> 16) & 1u;
    t.u += 0x7fffu + lsb;
    return (u16)(t.u >> 16);
}
__device__ __forceinline__ float sigm(float x) { return 1.f / (1.f + expf(-x)); }
__device__ __forceinline__ f16x2 packpair(float a, float b) {
    f16x2 r; r[0] = (_Float16)a; r[1] = (_Float16)b; return r;
}

__global__ void k_detect(const void* whh1) {
    if (threadIdx.x == 0 && blockIdx.x == 0) {
        const u16* p = (const u16*)whh1;
        int f32 = 0;
        for (int k = 0; k < 256; ++k) {
            float v = bf2f(p[2 * k]);
            if (!(fabsf(v) < 1e3f)) f32 = 1;
        }
        g_isf32 = f32;
    }
}

// Build fused/transposed/permuted f16 weights + biases; canonicalize inputs; zero state.
__global__ void k_convert(const void* inp,
                          const void* wih1, const void* bih1, const void* whh1, const void* bhh1,
                          const void* wih2, const void* bih2, const void* whh2, const void* bhh2,
                          const void* wih3, const void* bih3, const void* whh3, const void* bhh3,
                          const void* watt, const void* batt, const void* wgmm, const void* bgmm)
{
    const int gt = blockIdx.x * blockDim.x + threadIdx.x;
    const int gs = gridDim.x * blockDim.x;
    const int f32 = g_isf32;
    auto ld = [f32](const void* p, int i) -> float {
        return f32 ? ((const float*)p)[i] : bf2f(((const u16*)p)[i]);
    };
    auto w1col = [&](int kf, int row) -> float {
        if (kf < 400) return ld(whh1, row * 400 + kf);
        if (kf < 460) return ld(wih1, row * 63 + (kf - 400));
        if (kf < 463) return ld(wih1, row * 63 + 60 + (kf - 460));
        return 0.f;
    };
    auto w2col = [&](int kf, int row) -> float {
        if (kf < 400) return ld(wih2, row * 463 + 3 + kf);
        if (kf < 800) return ld(whh2, row * 400 + (kf - 400));
        if (kf < 860) return ld(wih2, row * 463 + 403 + (kf - 800));
        if (kf < 863) return ld(wih2, row * 463 + (kf - 860));
        return 0.f;
    };
    auto w3col = [&](int kf, int row) -> float {
        if (kf < 400)  return ld(wih3, row * 863 + 3 + kf);
        if (kf < 800)  return ld(wih3, row * 863 + 403 + (kf - 400));
        if (kf < 1200) return ld(whh3, row * 400 + (kf - 800));
        if (kf < 1260) return ld(wih3, row * 863 + 803 + (kf - 1200));
        if (kf < 1263) return ld(wih3, row * 863 + (kf - 1260));
        return 0.f;
    };
    for (int i = gt; i < 256 * ROWSP; i += gs) {
        int k2 = i / ROWSP, rp = i % ROWSP;
        int j = rp >> 2, g = rp & 3;
        float a = 0.f, b = 0.f;
        if (j < 400) { int row = g * 400 + j; a = w1col(2 * k2, row); b = w1col(2 * k2 + 1, row); }
        g_WT1[i] = packpair(a, b);
    }
    for (int i = gt; i < 448 * ROWSP; i += gs) {
        int k2 = i / ROWSP, rp = i % ROWSP;
        int j = rp >> 2, g = rp & 3;
        float a = 0.f, b = 0.f;
        if (j < 400) { int row = g * 400 + j; a = w2col(2 * k2, row); b = w2col(2 * k2 + 1, row); }
        g_WT2[i] = packpair(a, b);
    }
    for (int i = gt; i < 640 * ROWSP; i += gs) {
        int k2 = i / ROWSP, rp = i % ROWSP;
        int j = rp >> 2, g = rp & 3;
        float a = 0.f, b = 0.f;
        if (j < 400) { int row = g * 400 + j; a = w3col(2 * k2, row); b = w3col(2 * k2 + 1, row); }
        g_WT3[i] = packpair(a, b);
    }
    for (int i = gt; i < ROWSP; i += gs) {
        int j = i >> 2, g = i & 3;
        float b1 = 0.f, b2 = 0.f, b3 = 0.f;
        if (j < 400) {
            int row = g * 400 + j;
            b1 = ld(bih1, row) + ld(bhh1, row);
            b2 = ld(bih2, row) + ld(bhh2, row);
            b3 = ld(bih3, row) + ld(bhh3, row);
        }
        g_fb1[i] = b1; g_fb2[i] = b2; g_fb3[i] = b3;
    }
    for (int i = gt; i < 400 * 32; i += gs) {
        int k = i / 32, r = i % 32;
        g_WattT[i] = (r < 30) ? ld(watt, r * 400 + k) : 0.f;
    }
    for (int i = gt; i < 600 * 128; i += gs) {
        int k2 = i / 128, r = i % 128;
        float a = 0.f, b = 0.f;
        if (r < 121) { a = ld(wgmm, r * 1200 + 2 * k2); b = ld(wgmm, r * 1200 + 2 * k2 + 1); }
        g_WG2[i] = packpair(a, b);
    }
    for (int i = gt; i < 30; i += gs)  g_batt[i] = ld(batt, i);
    for (int i = gt; i < 121; i += gs) g_bgmm[i] = ld(bgmm, i);
    for (int i = gt; i < 115200; i += gs) g_inp[i] = ld(inp, i);
    for (int i = gt; i < ST_FLOATS; i += gs) g_state[i] = 0.f;
}

// Generic LSTM: 8 waves split K; lane = 2 rows x 8 batches; LDS atomic reduce; cell update.
template<int KP2>
__device__ __forceinline__ void lstm_core(const f16x2* __restrict__ WT, const float* __restrict__ fb,
                                          float* __restrict__ cst, float* __restrict__ hdst,
                                          const f16x2* inb, float* accS, int rg, int bg, int tid)
{
    const int wv = tid >> 6, lane = tid & 63;
    const int ck = KP2 >> 3;
    const int k0 = wv * ck, kend = k0 + ck;
    const int rbase = rg * 128 + lane * 2;
    float acc[2][8];
    #pragma unroll
    for (int r = 0; r < 2; ++r)
        #pragma unroll
        for (int b = 0; b < 8; ++b) acc[r][b] = 0.f;
    #pragma unroll 4
    for (int k2 = k0; k2 < kend; ++k2) {
        f16x4 w4 = *(const f16x4*)(WT + (size_t)k2 * ROWSP + rbase);
        f16x2 wa; wa[0] = w4[0]; wa[1] = w4[1];
        f16x2 wb; wb[0] = w4[2]; wb[1] = w4[3];
        #pragma unroll
        for (int b = 0; b < 8; ++b) {
            f16x2 hv = inb[b * KP2 + k2];
            acc[0][b] = FDOT2(wa, hv, acc[0][b]);
            acc[1][b] = FDOT2(wb, hv, acc[1][b]);
        }
    }
    #pragma unroll
    for (int r = 0; r < 2; ++r)
        #pragma unroll
        for (int b = 0; b < 8; ++b)
            atomicAdd(&accS[(lane * 2 + r) * 9 + b], acc[r][b]);
    __syncthreads();
    if (tid < 256) {
        int bl = tid >> 5, jj = tid & 31;
        int j = rg * 32 + jj;
        if (j < 400) {
            int rl = jj * 4;
            float gi = accS[(rl + 0) * 9 + bl] + fb[rg * 128 + rl + 0];
            float gf = accS[(rl + 1) * 9 + bl] + fb[rg * 128 + rl + 1];
            float gg = accS[(rl + 2) * 9 + bl] + fb[rg * 128 + rl + 2];
            float go = accS[(rl + 3) * 9 + bl] + fb[rg * 128 + rl + 3];
            int b = bg * 8 + bl;
            float c = cst[b * 400 + j];
            float cn = sigm(gf) * c + sigm(gi) * tanhf(gg);
            cst[b * 400 + j] = cn;
            hdst[b * 400 + j] = sigm(go) * tanhf(cn);
        }
    }
}

// GMM output head: 4 batches per block, transposed f16 weights, dot2.
__device__ void out_head(void* out, int tOut, int obid, int tid, char* smem)
{
    f16x2* zb = (f16x2*)smem;            // 4*600*4 = 9600
    float* zv = (float*)(smem + 9600);   // 1936
    const int pp = tOut & 1;
    const float* h1 = g_state + H1OFF + pp * (NB * NH);
    const float* h2 = g_state + H2OFF + pp * (NB * NH);
    const float* h3 = g_state + H3OFF + pp * (NB * NH);
    for (int i = tid; i < 4 * 600; i += 512) {
        int bq = i / 600, p = i % 600; int b = obid * 4 + bq;
        int kf = 2 * p;
        const float* src = (kf < 400) ? (h1 + b * 400 + kf)
                         : (kf < 800) ? (h2 + b * 400 + (kf - 400))
                                      : (h3 + b * 400 + (kf - 800));
        zb[bq * 600 + p] = packpair(src[0], src[1]);
    }
    __syncthreads();
    {
        int bq = tid >> 7, r = tid & 127;
        if (r < 121) {
            float acc = g_bgmm[r];
            const f16x2* zp = zb + bq * 600;
            #pragma unroll 4
            for (int k2 = 0; k2 < 600; ++k2)
                acc = FDOT2(g_WG2[k2 * 128 + r], zp[k2], acc);
            zv[bq * 121 + r] = acc;
        }
    }
    __syncthreads();
    if (tid < 484) {
        int bl = tid / 121, jo = tid - bl * 121;
        const float* z = zv + bl * 121;
        float val;
        if (jo < 20) {
            float m = -1e30f;
            for (int i = 0; i < 20; ++i) m = fmaxf(m, z[1 + i]);
            float s = 0.f;
            for (int i = 0; i < 20; ++i) s += expf(z[1 + i] - m);
            val = expf(z[1 + jo] - m) / s;
        } else if (jo < 60)  val = z[jo + 1];
        else if (jo < 100)   val = expf(z[jo + 1]);
        else if (jo < 120)   val = tanhf(z[jo + 1]);
        else                 val = 1.f / (1.f + expf(-z[0]));
        int idx = ((obid * 4 + bl) * NT + tOut) * NOUT + jo;
        if (g_isf32) ((float*)out)[idx] = val;
        else         ((u16*)out)[idx]  = f2bf(val);
    }
    __syncthreads();
}

__device__ void phaseA_lstm1(int t, int cur, int prev, int rg, int bg, int tid, char* smem)
{
    f16x2* inb = (f16x2*)smem;             // 8192
    float* accS = (float*)(smem + 8192);   // 4608
    const float* h1p = g_state + H1OFF + prev * (NB * NH);
    for (int i = tid; i < 8 * 256; i += 512) {
        int bl = i >> 8, p = i & 255; int b = bg * 8 + bl;
        float a = 0.f, v = 0.f;
        if (p < 200)      { a = h1p[b * 400 + 2 * p]; v = h1p[b * 400 + 2 * p + 1]; }
        else if (p < 230) { int q = p - 200;
                            a = g_state[WINOFF + b * 60 + 2 * q];
                            v = g_state[WINOFF + b * 60 + 2 * q + 1]; }
        else if (p == 230){ a = g_inp[(b * NT + t) * 3 + 0]; v = g_inp[(b * NT + t) * 3 + 1]; }
        else if (p == 231){ a = g_inp[(b * NT + t) * 3 + 2]; }
        inb[bl * 256 + p] = packpair(a, v);
    }
    for (int i = tid; i < 1152; i += 512) accS[i] = 0.f;
    __syncthreads();
    lstm_core<256>(g_WT1, g_fb1, g_state + C1OFF, g_state + H1OFF + cur * (NB * NH),
                   inb, accS, rg, bg, tid);
    __syncthreads();
}

__device__ void phaseB_att_lstm2(const int* __restrict__ cseq, const int* __restrict__ clen,
                                 int t, int cur, int prev, int rg, int bg, int tid, char* smem)
{
    f16x2* inb  = (f16x2*)smem;              // 14336
    float* h1f  = (float*)(smem + 14336);    // 12800
    float* accS = (float*)(smem + 27136);    // 4608
    float* ab   = (float*)(smem + 31744);    // 960
    float* phi  = (float*)(smem + 32704);    // 1600
    float* kap  = (float*)(smem + 34304);    // 320
    int*   chs  = (int*)  (smem + 34624);    // 1600
    int*   len  = (int*)  (smem + 36224);    // 32
    const float* h1  = g_state + H1OFF + cur  * (NB * NH);
    const float* h2p = g_state + H2OFF + prev * (NB * NH);
    for (int i = tid; i < 8 * 448; i += 512) {
        int bl = i / 448, p = i % 448; int b = bg * 8 + bl;
        float a = 0.f, v = 0.f;
        if (p < 200) {
            a = h1[b * 400 + 2 * p]; v = h1[b * 400 + 2 * p + 1];
            h1f[bl * 400 + 2 * p] = a; h1f[bl * 400 + 2 * p + 1] = v;
        }
        else if (p < 400) { int q = p - 200; a = h2p[b * 400 + 2 * q]; v = h2p[b * 400 + 2 * q + 1]; }
        else if (p == 430){ a = g_inp[(b * NT + t) * 3 + 0]; v = g_inp[(b * NT + t) * 3 + 1]; }
        else if (p == 431){ a = g_inp[(b * NT + t) * 3 + 2]; }
        inb[bl * 448 + p] = packpair(a, v);
    }
    for (int i = tid; i < 1152; i += 512) accS[i] = 0.f;
    if (tid < 80) { int bl = tid / 10, k = tid % 10;
        kap[tid] = g_state[KPOFF + prev * (NB * NKATT) + (bg * 8 + bl) * 10 + k]; }
    else if (tid >= 80 && tid < 480) { int i = tid - 80; int bl = i / 50, u = i % 50;
        chs[bl * 50 + u] = cseq[(bg * 8 + bl) * NTC + u]; }
    else if (tid >= 480 && tid < 488) len[tid - 480] = clen[bg * 8 + (tid - 480)];
    __syncthreads();
    if (tid < 240) {                       // p = exp(h1 @ W_att.T + b_att)
        int bl = tid / 30, rr = tid % 30;
        float acc = g_batt[rr];
        const float* hp = h1f + bl * 400;
        #pragma unroll 4
        for (int k = 0; k < 400; ++k) acc += g_WattT[k * 32 + rr] * hp[k];
        ab[bl * 30 + rr] = expf(acc);
    }
    __syncthreads();
    if (tid < 400) {                       // phi (length-masked)
        int bl = tid / 50, u = tid % 50;
        float ph = 0.f;
        if (u < len[bl]) {
            float uf = (float)u;
            for (int k = 0; k < 10; ++k) {
                float kn = kap[bl * 10 + k] + ab[bl * 30 + 20 + k];
                float d = kn - uf;
                ph += ab[bl * 30 + k] * expf(-ab[bl * 30 + 10 + k] * d * d);
            }
        }
        phi[bl * 50 + u] = ph;
    } else if (tid >= 400 && tid < 480 && rg == 0) {   // kappa writer
        int i = tid - 400; int bl = i / 10, k = i % 10;
        g_state[KPOFF + cur * (NB * NKATT) + (bg * 8 + bl) * 10 + k] =
            kap[bl * 10 + k] + ab[bl * 30 + 20 + k];
    }
    __syncthreads();
    if (tid < 240) {                       // window pairs -> inb + g_state
        int bl = tid / 30, q = tid % 30;
        int a0 = 2 * q, a1 = 2 * q + 1;
        float w0 = 0.f, w1 = 0.f;
        for (int u = 0; u < NTC; ++u) {
            float pv = phi[bl * 50 + u]; int cc = chs[bl * 50 + u];
            if (cc == a0) w0 += pv;
            if (cc == a1) w1 += pv;
        }
        inb[bl * 448 + 400 + q] = packpair(w0, w1);
        if (rg == 0) { int b = bg * 8 + bl;
            g_state[WINOFF + b * 60 + a0] = w0;
            g_state[WINOFF + b * 60 + a1] = w1; }
    }
    __syncthreads();
    lstm_core<448>(g_WT2, g_fb2, g_state + C2OFF, g_state + H2OFF + cur * (NB * NH),
                   inb, accS, rg, bg, tid);
    __syncthreads();
}

__device__ void phaseC_lstm3(int t, int cur, int prev, int rg, int bg, int tid, char* smem)
{
    f16x2* inb  = (f16x2*)smem;              // 20480
    float* accS = (float*)(smem + 20480);    // 4608
    const float* h1  = g_state + H1OFF + cur  * (NB * NH);
    const float* h2  = g_state + H2OFF + cur  * (NB * NH);
    const float* h3p = g_state + H3OFF + prev * (NB * NH);
    for (int i = tid; i < 8 * 640; i += 512) {
        int bl = i / 640, p = i % 640; int b = bg * 8 + bl;
        float a = 0.f, v = 0.f;
        if (p < 200)      { a = h1[b * 400 + 2 * p];  v = h1[b * 400 + 2 * p + 1]; }
        else if (p < 400) { int q = p - 200; a = h2[b * 400 + 2 * q];  v = h2[b * 400 + 2 * q + 1]; }
        else if (p < 600) { int q = p - 400; a = h3p[b * 400 + 2 * q]; v = h3p[b * 400 + 2 * q + 1]; }
        else if (p < 630) { int q = p - 600;
                            a = g_state[WINOFF + b * 60 + 2 * q];
                            v = g_state[WINOFF + b * 60 + 2 * q + 1]; }
        else if (p == 630){ a = g_inp[(b * NT + t) * 3 + 0]; v = g_inp[(b * NT + t) * 3 + 1]; }
        else if (p == 631){ a = g_inp[(b * NT + t) * 3 + 2]; }
        inb[bl * 640 + p] = packpair(a, v);
    }
    for (int i = tid; i < 1152; i += 512) accS[i] = 0.f;
    __syncthreads();
    lstm_core<640>(g_WT3, g_fb3, g_state + C3OFF, g_state + H3OFF + cur * (NB * NH),
                   inb, accS, rg, bg, tid);
    __syncthreads();
}

// Persistent cooperative kernel: blocks 0..103 LSTM workers (rg,bg), 104..119 head workers.
__global__ __launch_bounds__(512) void k_persist(void* out,
                                                 const int* __restrict__ cseq,
                                                 const int* __restrict__ clen)
{
    cg::grid_group grid = cg::this_grid();
    __shared__ __align__(16) char smem[36352];
    const int tid = threadIdx.x;
    const int bid = blockIdx.x;
    const bool isL = (bid < 104);
    const int rg = bid % 13, bg = bid / 13;
    for (int t = 0; t < NT; ++t) {
        const int cur = t & 1, prev = cur ^ 1;
        // Phase A: LSTM1 + GMM head for t-1
        if (isL)          phaseA_lstm1(t, cur, prev, rg, bg, tid, smem);
        else if (t > 0)   out_head(out, t - 1, bid - 104, tid, smem);
        grid.sync();
        // Phase B: attention (per-block recompute) + LSTM2
        if (isL)          phaseB_att_lstm2(cseq, clen, t, cur, prev, rg, bg, tid, smem);
        grid.sync();
        // Phase C: LSTM3
        if (isL)          phaseC_lstm3(t, cur, prev, rg, bg, tid, smem);
        grid.sync();
    }
    if (!isL) out_head(out, NT - 1, bid - 104, tid, smem);
}

extern "C" void kernel_launch(void* const* d_in, const int* in_sizes, int n_in,
                              void* d_out, int out_size, void* d_ws, size_t ws_size,
                              hipStream_t stream)
{
    hipLaunchKernelGGL(k_detect, dim3(1), dim3(64), 0, stream, d_in[5]);  // W_hh1
    hipLaunchKernelGGL(k_convert, dim3(2048), dim3(256), 0, stream,
                       d_in[0],
                       d_in[3], d_in[4], d_in[5], d_in[6],
                       d_in[7], d_in[8], d_in[9], d_in[10],
                       d_in[11], d_in[12], d_in[13], d_in[14],
                       d_in[15], d_in[16], d_in[17], d_in[18]);
    void* outp = d_out;
    const int* cseq = (const int*)d_in[1];
    const int* clen = (const int*)d_in[2];
    void* args[] = { (void*)&outp, (void*)&cseq, (void*)&clen };
    hipLaunchCooperativeKernel((void*)k_persist, dim3(120), dim3(512), args, 0, stream);
}

// Round 5
// 76217.755 us; speedup vs baseline: 1.2310x; 1.2310x over previous
//
#include <hip/hip_runtime.h>
#include <hip/hip_bf16.h>

#define NB 64
#define NT 600
#define NTC 50
#define NH 400
#define NKATT 10
#define NALPHA 60
#define NOUT 121

typedef unsigned short u16;
typedef _Float16 f16x2 __attribute__((ext_vector_type(2)));
typedef _Float16 f16x4 __attribute__((ext_vector_type(4)));

#if defined(__has_builtin)
#if __has_builtin(__builtin_amdgcn_fdot2)
#define FDOT2(a,b,c) __builtin_amdgcn_fdot2((a),(b),(c),false)
#endif
#endif
#ifndef FDOT2
#define FDOT2(a,b,c) ((c) + (float)(a)[0]*(float)(b)[0] + (float)(a)[1]*(float)(b)[1])
#endif

// Padded fused-K sizes (pairs): K1=512->256, K2=896->448, K3=1280->640. Rows padded 1600->1664.
#define ROWSP 1664
#define GRPB 15            // blocks per batch-group barrier: 13 LSTM + 2 head

// state layout (floats)
#define H1OFF 0            // [2][NB][NH] ping-pong
#define H2OFF 51200
#define H3OFF 102400
#define C1OFF 153600
#define C2OFF 179200
#define C3OFF 204800
#define KPOFF 230400       // [2][NB][NKATT]
#define WINOFF 231680      // [NB][NALPHA]
#define ST_FLOATS 235520

__device__ __align__(16) f16x2 g_WT1[256 * ROWSP];
__device__ __align__(16) f16x2 g_WT2[448 * ROWSP];
__device__ __align__(16) f16x2 g_WT3[640 * ROWSP];
__device__ __align__(16) f16x2 g_WG2[600 * 128];
__device__ __align__(16) float g_fb1[ROWSP], g_fb2[ROWSP], g_fb3[ROWSP];
__device__ __align__(16) float g_WattT[400 * 32];
__device__ float g_batt[30], g_bgmm[121];
__device__ __align__(16) float g_inp[115200];
__device__ float g_state[ST_FLOATS];
__device__ unsigned int g_barcnt[8];
__device__ int   g_isf32;

__device__ __forceinline__ float bf2f(u16 v) {
    union { unsigned int u; float f; } t; t.u = ((unsigned int)v) << 16; return t.f;
}
__device__ __forceinline__ u16 f2bf(float f) {
    union { float ff; unsigned int u; } t; t.ff = f;
    unsigned int lsb = (t.u >> 16) & 1u;
    t.u += 0x7fffu + lsb;
    return (u16)(t.u >> 16);
}
__device__ __forceinline__ float sigm(float x) { return 1.f / (1.f + expf(-x)); }
__device__ __forceinline__ f16x2 packpair(float a, float b) {
    f16x2 r; r[0] = (_Float16)a; r[1] = (_Float16)b; return r;
}

// ---- agent-scope (cross-XCD coherent, LLC-direct) state accessors ----
__device__ __forceinline__ float ld_agent(const float* p) {
    return __hip_atomic_load(p, __ATOMIC_RELAXED, __HIP_MEMORY_SCOPE_AGENT);
}
__device__ __forceinline__ void st_agent(float* p, float v) {
    __hip_atomic_store(p, v, __ATOMIC_RELAXED, __HIP_MEMORY_SCOPE_AGENT);
}
__device__ __forceinline__ float2 ld2_agent(const float* p) {
    unsigned long long u = __hip_atomic_load((const unsigned long long*)p,
                                             __ATOMIC_RELAXED, __HIP_MEMORY_SCOPE_AGENT);
    union { unsigned long long u; float2 f; } t; t.u = u; return t.f;
}

// Per-batch-group barrier over GRPB blocks. All cross-block data uses sc1 (LLC-direct)
// stores, and __syncthreads drains each wave's vmcnt, so no L2 writeback fence is needed.
__device__ __forceinline__ void bg_barrier(int bg, unsigned* bars) {
    __syncthreads();
    ++(*bars);
    if (threadIdx.x == 0) {
        unsigned tgt = (unsigned)GRPB * (*bars);
        __hip_atomic_fetch_add(&g_barcnt[bg], 1u, __ATOMIC_RELAXED, __HIP_MEMORY_SCOPE_AGENT);
        while (__hip_atomic_load(&g_barcnt[bg], __ATOMIC_RELAXED, __HIP_MEMORY_SCOPE_AGENT) < tgt)
            __builtin_amdgcn_s_sleep(1);
    }
    __syncthreads();
}

__global__ void k_detect(const void* whh1) {
    if (threadIdx.x == 0 && blockIdx.x == 0) {
        const u16* p = (const u16*)whh1;
        int f32 = 0;
        for (int k = 0; k < 256; ++k) {
            float v = bf2f(p[2 * k]);
            if (!(fabsf(v) < 1e3f)) f32 = 1;
        }
        g_isf32 = f32;
    }
}

// Build fused/transposed/permuted f16 weights + biases; canonicalize inputs; zero state.
__global__ void k_convert(const void* inp,
                          const void* wih1, const void* bih1, const void* whh1, const void* bhh1,
                          const void* wih2, const void* bih2, const void* whh2, const void* bhh2,
                          const void* wih3, const void* bih3, const void* whh3, const void* bhh3,
                          const void* watt, const void* batt, const void* wgmm, const void* bgmm)
{
    const int gt = blockIdx.x * blockDim.x + threadIdx.x;
    const int gs = gridDim.x * blockDim.x;
    const int f32 = g_isf32;
    auto ld = [f32](const void* p, int i) -> float {
        return f32 ? ((const float*)p)[i] : bf2f(((const u16*)p)[i]);
    };
    auto w1col = [&](int kf, int row) -> float {
        if (kf < 400) return ld(whh1, row * 400 + kf);
        if (kf < 460) return ld(wih1, row * 63 + (kf - 400));
        if (kf < 463) return ld(wih1, row * 63 + 60 + (kf - 460));
        return 0.f;
    };
    auto w2col = [&](int kf, int row) -> float {
        if (kf < 400) return ld(wih2, row * 463 + 3 + kf);
        if (kf < 800) return ld(whh2, row * 400 + (kf - 400));
        if (kf < 860) return ld(wih2, row * 463 + 403 + (kf - 800));
        if (kf < 863) return ld(wih2, row * 463 + (kf - 860));
        return 0.f;
    };
    auto w3col = [&](int kf, int row) -> float {
        if (kf < 400)  return ld(wih3, row * 863 + 3 + kf);
        if (kf < 800)  return ld(wih3, row * 863 + 403 + (kf - 400));
        if (kf < 1200) return ld(whh3, row * 400 + (kf - 800));
        if (kf < 1260) return ld(wih3, row * 863 + 803 + (kf - 1200));
        if (kf < 1263) return ld(wih3, row * 863 + (kf - 1260));
        return 0.f;
    };
    for (int i = gt; i < 256 * ROWSP; i += gs) {
        int k2 = i / ROWSP, rp = i % ROWSP;
        int j = rp >> 2, g = rp & 3;
        float a = 0.f, b = 0.f;
        if (j < 400) { int row = g * 400 + j; a = w1col(2 * k2, row); b = w1col(2 * k2 + 1, row); }
        g_WT1[i] = packpair(a, b);
    }
    for (int i = gt; i < 448 * ROWSP; i += gs) {
        int k2 = i / ROWSP, rp = i % ROWSP;
        int j = rp >> 2, g = rp & 3;
        float a = 0.f, b = 0.f;
        if (j < 400) { int row = g * 400 + j; a = w2col(2 * k2, row); b = w2col(2 * k2 + 1, row); }
        g_WT2[i] = packpair(a, b);
    }
    for (int i = gt; i < 640 * ROWSP; i += gs) {
        int k2 = i / ROWSP, rp = i % ROWSP;
        int j = rp >> 2, g = rp & 3;
        float a = 0.f, b = 0.f;
        if (j < 400) { int row = g * 400 + j; a = w3col(2 * k2, row); b = w3col(2 * k2 + 1, row); }
        g_WT3[i] = packpair(a, b);
    }
    for (int i = gt; i < ROWSP; i += gs) {
        int j = i >> 2, g = i & 3;
        float b1 = 0.f, b2 = 0.f, b3 = 0.f;
        if (j < 400) {
            int row = g * 400 + j;
            b1 = ld(bih1, row) + ld(bhh1, row);
            b2 = ld(bih2, row) + ld(bhh2, row);
            b3 = ld(bih3, row) + ld(bhh3, row);
        }
        g_fb1[i] = b1; g_fb2[i] = b2; g_fb3[i] = b3;
    }
    for (int i = gt; i < 400 * 32; i += gs) {
        int k = i / 32, r = i % 32;
        g_WattT[i] = (r < 30) ? ld(watt, r * 400 + k) : 0.f;
    }
    for (int i = gt; i < 600 * 128; i += gs) {
        int k2 = i / 128, r = i % 128;
        float a = 0.f, b = 0.f;
        if (r < 121) { a = ld(wgmm, r * 1200 + 2 * k2); b = ld(wgmm, r * 1200 + 2 * k2 + 1); }
        g_WG2[i] = packpair(a, b);
    }
    for (int i = gt; i < 30; i += gs)  g_batt[i] = ld(batt, i);
    for (int i = gt; i < 121; i += gs) g_bgmm[i] = ld(bgmm, i);
    for (int i = gt; i < 115200; i += gs) g_inp[i] = ld(inp, i);
    for (int i = gt; i < ST_FLOATS; i += gs) g_state[i] = 0.f;
    for (int i = gt; i < 8; i += gs) g_barcnt[i] = 0u;
}

// Generic LSTM: 8 waves split K; lane = 2 rows x 8 batches; LDS atomic reduce; cell update.
template<int KP2>
__device__ __forceinline__ void lstm_core(const f16x2* __restrict__ WT, const float* __restrict__ fb,
                                          float* __restrict__ cst, float* __restrict__ hdst,
                                          const f16x2* inb, float* accS, int rg, int bg, int tid)
{
    const int wv = tid >> 6, lane = tid & 63;
    const int ck = KP2 >> 3;
    const int k0 = wv * ck, kend = k0 + ck;
    const int rbase = rg * 128 + lane * 2;
    float acc[2][8];
    #pragma unroll
    for (int r = 0; r < 2; ++r)
        #pragma unroll
        for (int b = 0; b < 8; ++b) acc[r][b] = 0.f;
    #pragma unroll 4
    for (int k2 = k0; k2 < kend; ++k2) {
        f16x4 w4 = *(const f16x4*)(WT + (size_t)k2 * ROWSP + rbase);
        f16x2 wa; wa[0] = w4[0]; wa[1] = w4[1];
        f16x2 wb; wb[0] = w4[2]; wb[1] = w4[3];
        #pragma unroll
        for (int b = 0; b < 8; ++b) {
            f16x2 hv = inb[b * KP2 + k2];
            acc[0][b] = FDOT2(wa, hv, acc[0][b]);
            acc[1][b] = FDOT2(wb, hv, acc[1][b]);
        }
    }
    #pragma unroll
    for (int r = 0; r < 2; ++r)
        #pragma unroll
        for (int b = 0; b < 8; ++b)
            atomicAdd(&accS[(lane * 2 + r) * 9 + b], acc[r][b]);
    __syncthreads();
    if (tid < 256) {
        int bl = tid >> 5, jj = tid & 31;
        int j = rg * 32 + jj;
        if (j < 400) {
            int rl = jj * 4;
            float gi = accS[(rl + 0) * 9 + bl] + fb[rg * 128 + rl + 0];
            float gf = accS[(rl + 1) * 9 + bl] + fb[rg * 128 + rl + 1];
            float gg = accS[(rl + 2) * 9 + bl] + fb[rg * 128 + rl + 2];
            float go = accS[(rl + 3) * 9 + bl] + fb[rg * 128 + rl + 3];
            int b = bg * 8 + bl;
            float c = cst[b * 400 + j];               // owner-exclusive: plain
            float cn = sigm(gf) * c + sigm(gi) * tanhf(gg);
            cst[b * 400 + j] = cn;
            st_agent(&hdst[b * 400 + j], sigm(go) * tanhf(cn));  // cross-block: LLC
        }
    }
}

// GMM output head: 4 batches per block, transposed f16 weights, dot2.
__device__ void out_head(void* out, int tOut, int obid, int tid, char* smem)
{
    f16x2* zb = (f16x2*)smem;            // 4*600*4 = 9600
    float* zv = (float*)(smem + 9600);   // 1936
    const int pp = tOut & 1;
    const float* h1 = g_state + H1OFF + pp * (NB * NH);
    const float* h2 = g_state + H2OFF + pp * (NB * NH);
    const float* h3 = g_state + H3OFF + pp * (NB * NH);
    for (int i = tid; i < 4 * 600; i += 512) {
        int bq = i / 600, p = i % 600; int b = obid * 4 + bq;
        int kf = 2 * p;
        const float* src = (kf < 400) ? (h1 + b * 400 + kf)
                         : (kf < 800) ? (h2 + b * 400 + (kf - 400))
                                      : (h3 + b * 400 + (kf - 800));
        float2 hv = ld2_agent(src);
        zb[bq * 600 + p] = packpair(hv.x, hv.y);
    }
    __syncthreads();
    {
        int bq = tid >> 7, r = tid & 127;
        if (r < 121) {
            float acc = g_bgmm[r];
            const f16x2* zp = zb + bq * 600;
            #pragma unroll 4
            for (int k2 = 0; k2 < 600; ++k2)
                acc = FDOT2(g_WG2[k2 * 128 + r], zp[k2], acc);
            zv[bq * 121 + r] = acc;
        }
    }
    __syncthreads();
    if (tid < 484) {
        int bl = tid / 121, jo = tid - bl * 121;
        const float* z = zv + bl * 121;
        float val;
        if (jo < 20) {
            float m = -1e30f;
            for (int i = 0; i < 20; ++i) m = fmaxf(m, z[1 + i]);
            float s = 0.f;
            for (int i = 0; i < 20; ++i) s += expf(z[1 + i] - m);
            val = expf(z[1 + jo] - m) / s;
        } else if (jo < 60)  val = z[jo + 1];
        else if (jo < 100)   val = expf(z[jo + 1]);
        else if (jo < 120)   val = tanhf(z[jo + 1]);
        else                 val = 1.f / (1.f + expf(-z[0]));
        int idx = ((obid * 4 + bl) * NT + tOut) * NOUT + jo;
        if (g_isf32) ((float*)out)[idx] = val;
        else         ((u16*)out)[idx]  = f2bf(val);
    }
    __syncthreads();
}

__device__ void phaseA_lstm1(int t, int cur, int prev, int rg, int bg, int tid, char* smem)
{
    f16x2* inb = (f16x2*)smem;             // 8192
    float* accS = (float*)(smem + 8192);   // 4608
    const float* h1p = g_state + H1OFF + prev * (NB * NH);
    for (int i = tid; i < 8 * 256; i += 512) {
        int bl = i >> 8, p = i & 255; int b = bg * 8 + bl;
        float a = 0.f, v = 0.f;
        if (p < 200)      { float2 hv = ld2_agent(h1p + b * 400 + 2 * p); a = hv.x; v = hv.y; }
        else if (p < 230) { int q = p - 200;
                            float2 wv = ld2_agent(g_state + WINOFF + b * 60 + 2 * q);
                            a = wv.x; v = wv.y; }
        else if (p == 230){ a = g_inp[(b * NT + t) * 3 + 0]; v = g_inp[(b * NT + t) * 3 + 1]; }
        else if (p == 231){ a = g_inp[(b * NT + t) * 3 + 2]; }
        inb[bl * 256 + p] = packpair(a, v);
    }
    for (int i = tid; i < 1152; i += 512) accS[i] = 0.f;
    __syncthreads();
    lstm_core<256>(g_WT1, g_fb1, g_state + C1OFF, g_state + H1OFF + cur * (NB * NH),
                   inb, accS, rg, bg, tid);
}

__device__ void phaseB_att_lstm2(const int* __restrict__ cseq, const int* __restrict__ clen,
                                 int t, int cur, int prev, int rg, int bg, int tid, char* smem)
{
    f16x2* inb  = (f16x2*)smem;              // 14336
    float* h1f  = (float*)(smem + 14336);    // 12800
    float* accS = (float*)(smem + 27136);    // 4608
    float* ab   = (float*)(smem + 31744);    // 960
    float* phi  = (float*)(smem + 32704);    // 1600
    float* kap  = (float*)(smem + 34304);    // 320
    int*   chs  = (int*)  (smem + 34624);    // 1600
    int*   len  = (int*)  (smem + 36224);    // 32
    const float* h1  = g_state + H1OFF + cur  * (NB * NH);
    const float* h2p = g_state + H2OFF + prev * (NB * NH);
    for (int i = tid; i < 8 * 448; i += 512) {
        int bl = i / 448, p = i % 448; int b = bg * 8 + bl;
        float a = 0.f, v = 0.f;
        if (p < 200) {
            float2 hv = ld2_agent(h1 + b * 400 + 2 * p); a = hv.x; v = hv.y;
            h1f[bl * 400 + 2 * p] = a; h1f[bl * 400 + 2 * p + 1] = v;
        }
        else if (p < 400) { int q = p - 200;
                            float2 hv = ld2_agent(h2p + b * 400 + 2 * q); a = hv.x; v = hv.y; }
        else if (p == 430){ a = g_inp[(b * NT + t) * 3 + 0]; v = g_inp[(b * NT + t) * 3 + 1]; }
        else if (p == 431){ a = g_inp[(b * NT + t) * 3 + 2]; }
        inb[bl * 448 + p] = packpair(a, v);
    }
    for (int i = tid; i < 1152; i += 512) accS[i] = 0.f;
    if (tid < 80) { int bl = tid / 10, k = tid % 10;
        kap[tid] = ld_agent(g_state + KPOFF + prev * (NB * NKATT) + (bg * 8 + bl) * 10 + k); }
    else if (tid >= 80 && tid < 480) { int i = tid - 80; int bl = i / 50, u = i % 50;
        chs[bl * 50 + u] = cseq[(bg * 8 + bl) * NTC + u]; }
    else if (tid >= 480 && tid < 488) len[tid - 480] = clen[bg * 8 + (tid - 480)];
    __syncthreads();
    if (tid < 240) {                       // p = exp(h1 @ W_att.T + b_att)
        int bl = tid / 30, rr = tid % 30;
        float acc = g_batt[rr];
        const float* hp = h1f + bl * 400;
        #pragma unroll 4
        for (int k = 0; k < 400; ++k) acc += g_WattT[k * 32 + rr] * hp[k];
        ab[bl * 30 + rr] = expf(acc);
    }
    __syncthreads();
    if (tid < 400) {                       // phi (length-masked)
        int bl = tid / 50, u = tid % 50;
        float ph = 0.f;
        if (u < len[bl]) {
            float uf = (float)u;
            for (int k = 0; k < 10; ++k) {
                float kn = kap[bl * 10 + k] + ab[bl * 30 + 20 + k];
                float d = kn - uf;
                ph += ab[bl * 30 + k] * expf(-ab[bl * 30 + 10 + k] * d * d);
            }
        }
        phi[bl * 50 + u] = ph;
    } else if (tid >= 400 && tid < 480 && rg == 0) {   // kappa writer
        int i = tid - 400; int bl = i / 10, k = i % 10;
        st_agent(g_state + KPOFF + cur * (NB * NKATT) + (bg * 8 + bl) * 10 + k,
                 kap[bl * 10 + k] + ab[bl * 30 + 20 + k]);
    }
    __syncthreads();
    if (tid < 240) {                       // window pairs -> inb + g_state
        int bl = tid / 30, q = tid % 30;
        int a0 = 2 * q, a1 = 2 * q + 1;
        float w0 = 0.f, w1 = 0.f;
        for (int u = 0; u < NTC; ++u) {
            float pv = phi[bl * 50 + u]; int cc = chs[bl * 50 + u];
            if (cc == a0) w0 += pv;
            if (cc == a1) w1 += pv;
        }
        inb[bl * 448 + 400 + q] = packpair(w0, w1);
        if (rg == 0) { int b = bg * 8 + bl;
            st_agent(g_state + WINOFF + b * 60 + a0, w0);
            st_agent(g_state + WINOFF + b * 60 + a1, w1); }
    }
    __syncthreads();
    lstm_core<448>(g_WT2, g_fb2, g_state + C2OFF, g_state + H2OFF + cur * (NB * NH),
                   inb, accS, rg, bg, tid);
}

__device__ void phaseC_lstm3(int t, int cur, int prev, int rg, int bg, int tid, char* smem)
{
    f16x2* inb  = (f16x2*)smem;              // 20480
    float* accS = (float*)(smem + 20480);    // 4608
    const float* h1  = g_state + H1OFF + cur  * (NB * NH);
    const float* h2  = g_state + H2OFF + cur  * (NB * NH);
    const float* h3p = g_state + H3OFF + prev * (NB * NH);
    for (int i = tid; i < 8 * 640; i += 512) {
        int bl = i / 640, p = i % 640; int b = bg * 8 + bl;
        float a = 0.f, v = 0.f;
        if (p < 200)      { float2 hv = ld2_agent(h1 + b * 400 + 2 * p); a = hv.x; v = hv.y; }
        else if (p < 400) { int q = p - 200; float2 hv = ld2_agent(h2 + b * 400 + 2 * q); a = hv.x; v = hv.y; }
        else if (p < 600) { int q = p - 400; float2 hv = ld2_agent(h3p + b * 400 + 2 * q); a = hv.x; v = hv.y; }
        else if (p < 630) { int q = p - 600;
                            float2 wv = ld2_agent(g_state + WINOFF + b * 60 + 2 * q);
                            a = wv.x; v = wv.y; }
        else if (p == 630){ a = g_inp[(b * NT + t) * 3 + 0]; v = g_inp[(b * NT + t) * 3 + 1]; }
        else if (p == 631){ a = g_inp[(b * NT + t) * 3 + 2]; }
        inb[bl * 640 + p] = packpair(a, v);
    }
    for (int i = tid; i < 1152; i += 512) accS[i] = 0.f;
    __syncthreads();
    lstm_core<640>(g_WT3, g_fb3, g_state + C3OFF, g_state + H3OFF + cur * (NB * NH),
                   inb, accS, rg, bg, tid);
}

// Persistent kernel: blocks 0..103 LSTM workers (rg,bg), 104..119 head workers (2 per bg).
// Synchronization: per-batch-group monotonic barriers (15 blocks each) — no grid.sync.
__global__ __launch_bounds__(512) void k_persist(void* out,
                                                 const int* __restrict__ cseq,
                                                 const int* __restrict__ clen)
{
    __shared__ __align__(16) char smem[36352];
    const int tid = threadIdx.x;
    const int bid = blockIdx.x;
    const bool isL = (bid < 104);
    const int rg = isL ? (bid % 13) : 0;
    const int bg = isL ? (bid / 13) : ((bid - 104) >> 1);
    unsigned bars = 0;
    for (int t = 0; t < NT; ++t) {
        const int cur = t & 1, prev = cur ^ 1;
        // Phase A: LSTM1 + GMM head for t-1
        if (isL)          phaseA_lstm1(t, cur, prev, rg, bg, tid, smem);
        else if (t > 0)   out_head(out, t - 1, bid - 104, tid, smem);
        bg_barrier(bg, &bars);
        // Phase B: attention (per-block recompute) + LSTM2
        if (isL)          phaseB_att_lstm2(cseq, clen, t, cur, prev, rg, bg, tid, smem);
        bg_barrier(bg, &bars);
        // Phase C: LSTM3
        if (isL)          phaseC_lstm3(t, cur, prev, rg, bg, tid, smem);
        bg_barrier(bg, &bars);
    }
    if (!isL) out_head(out, NT - 1, bid - 104, tid, smem);
}

extern "C" void kernel_launch(void* const* d_in, const int* in_sizes, int n_in,
                              void* d_out, int out_size, void* d_ws, size_t ws_size,
                              hipStream_t stream)
{
    hipLaunchKernelGGL(k_detect, dim3(1), dim3(64), 0, stream, d_in[5]);  // W_hh1
    hipLaunchKernelGGL(k_convert, dim3(2048), dim3(256), 0, stream,
                       d_in[0],
                       d_in[3], d_in[4], d_in[5], d_in[6],
                       d_in[7], d_in[8], d_in[9], d_in[10],
                       d_in[11], d_in[12], d_in[13], d_in[14],
                       d_in[15], d_in[16], d_in[17], d_in[18]);
    void* outp = d_out;
    const int* cseq = (const int*)d_in[1];
    const int* clen = (const int*)d_in[2];
    void* args[] = { (void*)&outp, (void*)&cseq, (void*)&clen };
    hipLaunchCooperativeKernel((void*)k_persist, dim3(120), dim3(512), args, 0, stream);
}

// Round 6
// 59459.314 us; speedup vs baseline: 1.5780x; 1.2818x over previous
//
#include <hip/hip_runtime.h>
#include <hip/hip_bf16.h>

#define NB 64
#define NT 600
#define NTC 50
#define NH 400
#define NKATT 10
#define NALPHA 60
#define NOUT 121

typedef unsigned short u16;
typedef _Float16 f16x2 __attribute__((ext_vector_type(2)));
typedef _Float16 f16x4 __attribute__((ext_vector_type(4)));
typedef _Float16 f16x8 __attribute__((ext_vector_type(8)));

#if defined(__has_builtin)
#if __has_builtin(__builtin_amdgcn_fdot2)
#define FDOT2(a,b,c) __builtin_amdgcn_fdot2((a),(b),(c),false)
#endif
#endif
#ifndef FDOT2
#define FDOT2(a,b,c) ((c) + (float)(a)[0]*(float)(b)[0] + (float)(a)[1]*(float)(b)[1])
#endif

// Padded fused-K sizes (pairs): K1=512->256, K2=896->448, K3=1280->640. Rows padded 1600->1664.
#define ROWSP 1664
#define GRPB 15            // blocks per batch-group barrier: 13 LSTM + 2 head

// state layout (floats)
#define H1OFF 0            // [2][NB][NH] ping-pong
#define H2OFF 51200
#define H3OFF 102400
#define C1OFF 153600
#define C2OFF 179200
#define C3OFF 204800
#define KPOFF 230400       // [2][NB][NKATT]
#define WINOFF 231680      // [NB][NALPHA]
#define ST_FLOATS 235520

__device__ __align__(16) f16x2 g_WT1[256 * ROWSP];
__device__ __align__(16) f16x2 g_WT2[448 * ROWSP];
__device__ __align__(16) f16x2 g_WT3[640 * ROWSP];
__device__ __align__(16) f16x2 g_WG2[600 * 128];
__device__ __align__(16) float g_fb1[ROWSP], g_fb2[ROWSP], g_fb3[ROWSP];
__device__ __align__(16) float g_WattT[400 * 32];
__device__ float g_batt[30], g_bgmm[121];
__device__ __align__(16) float g_inp[115200];
__device__ float g_state[ST_FLOATS];
__device__ unsigned int g_barcnt[8 * 32];   // one cacheline per batch-group
__device__ int   g_isf32;

__device__ __forceinline__ float bf2f(u16 v) {
    union { unsigned int u; float f; } t; t.u = ((unsigned int)v) << 16; return t.f;
}
__device__ __forceinline__ u16 f2bf(float f) {
    union { float ff; unsigned int u; } t; t.ff = f;
    unsigned int lsb = (t.u >> 16) & 1u;
    t.u += 0x7fffu + lsb;
    return (u16)(t.u >> 16);
}
__device__ __forceinline__ float sigm(float x) { return 1.f / (1.f + expf(-x)); }
__device__ __forceinline__ f16x2 packpair(float a, float b) {
    f16x2 r; r[0] = (_Float16)a; r[1] = (_Float16)b; return r;
}

// ---- agent-scope (cross-XCD coherent, LLC-direct) state accessors ----
__device__ __forceinline__ float ld_agent(const float* p) {
    return __hip_atomic_load(p, __ATOMIC_RELAXED, __HIP_MEMORY_SCOPE_AGENT);
}
__device__ __forceinline__ void st_agent(float* p, float v) {
    __hip_atomic_store(p, v, __ATOMIC_RELAXED, __HIP_MEMORY_SCOPE_AGENT);
}
__device__ __forceinline__ float2 ld2_agent(const float* p) {
    unsigned long long u = __hip_atomic_load((const unsigned long long*)p,
                                             __ATOMIC_RELAXED, __HIP_MEMORY_SCOPE_AGENT);
    union { unsigned long long u; float2 f; } t; t.u = u; return t.f;
}

// Per-batch-group barrier over GRPB blocks (LLC-direct sc1 data + vmcnt drain at syncthreads).
__device__ __forceinline__ void bg_barrier(int bg, unsigned* bars) {
    __syncthreads();
    ++(*bars);
    if (threadIdx.x == 0) {
        unsigned tgt = (unsigned)GRPB * (*bars);
        __hip_atomic_fetch_add(&g_barcnt[bg * 32], 1u, __ATOMIC_RELAXED, __HIP_MEMORY_SCOPE_AGENT);
        while (__hip_atomic_load(&g_barcnt[bg * 32], __ATOMIC_RELAXED, __HIP_MEMORY_SCOPE_AGENT) < tgt)
            __builtin_amdgcn_s_sleep(1);
    }
    __syncthreads();
}

__global__ void k_detect(const void* whh1) {
    if (threadIdx.x == 0 && blockIdx.x == 0) {
        const u16* p = (const u16*)whh1;
        int f32 = 0;
        for (int k = 0; k < 256; ++k) {
            float v = bf2f(p[2 * k]);
            if (!(fabsf(v) < 1e3f)) f32 = 1;
        }
        g_isf32 = f32;
    }
}

// Build fused/transposed/permuted f16 weights + biases; canonicalize inputs; zero state.
__global__ void k_convert(const void* inp,
                          const void* wih1, const void* bih1, const void* whh1, const void* bhh1,
                          const void* wih2, const void* bih2, const void* whh2, const void* bhh2,
                          const void* wih3, const void* bih3, const void* whh3, const void* bhh3,
                          const void* watt, const void* batt, const void* wgmm, const void* bgmm)
{
    const int gt = blockIdx.x * blockDim.x + threadIdx.x;
    const int gs = gridDim.x * blockDim.x;
    const int f32 = g_isf32;
    auto ld = [f32](const void* p, int i) -> float {
        return f32 ? ((const float*)p)[i] : bf2f(((const u16*)p)[i]);
    };
    auto w1col = [&](int kf, int row) -> float {
        if (kf < 400) return ld(whh1, row * 400 + kf);
        if (kf < 460) return ld(wih1, row * 63 + (kf - 400));
        if (kf < 463) return ld(wih1, row * 63 + 60 + (kf - 460));
        return 0.f;
    };
    auto w2col = [&](int kf, int row) -> float {
        if (kf < 400) return ld(wih2, row * 463 + 3 + kf);
        if (kf < 800) return ld(whh2, row * 400 + (kf - 400));
        if (kf < 860) return ld(wih2, row * 463 + 403 + (kf - 800));
        if (kf < 863) return ld(wih2, row * 463 + (kf - 860));
        return 0.f;
    };
    auto w3col = [&](int kf, int row) -> float {
        if (kf < 400)  return ld(wih3, row * 863 + 3 + kf);
        if (kf < 800)  return ld(wih3, row * 863 + 403 + (kf - 400));
        if (kf < 1200) return ld(whh3, row * 400 + (kf - 800));
        if (kf < 1260) return ld(wih3, row * 863 + 803 + (kf - 1200));
        if (kf < 1263) return ld(wih3, row * 863 + (kf - 1260));
        return 0.f;
    };
    for (int i = gt; i < 256 * ROWSP; i += gs) {
        int k2 = i / ROWSP, rp = i % ROWSP;
        int j = rp >> 2, g = rp & 3;
        float a = 0.f, b = 0.f;
        if (j < 400) { int row = g * 400 + j; a = w1col(2 * k2, row); b = w1col(2 * k2 + 1, row); }
        g_WT1[i] = packpair(a, b);
    }
    for (int i = gt; i < 448 * ROWSP; i += gs) {
        int k2 = i / ROWSP, rp = i % ROWSP;
        int j = rp >> 2, g = rp & 3;
        float a = 0.f, b = 0.f;
        if (j < 400) { int row = g * 400 + j; a = w2col(2 * k2, row); b = w2col(2 * k2 + 1, row); }
        g_WT2[i] = packpair(a, b);
    }
    for (int i = gt; i < 640 * ROWSP; i += gs) {
        int k2 = i / ROWSP, rp = i % ROWSP;
        int j = rp >> 2, g = rp & 3;
        float a = 0.f, b = 0.f;
        if (j < 400) { int row = g * 400 + j; a = w3col(2 * k2, row); b = w3col(2 * k2 + 1, row); }
        g_WT3[i] = packpair(a, b);
    }
    for (int i = gt; i < ROWSP; i += gs) {
        int j = i >> 2, g = i & 3;
        float b1 = 0.f, b2 = 0.f, b3 = 0.f;
        if (j < 400) {
            int row = g * 400 + j;
            b1 = ld(bih1, row) + ld(bhh1, row);
            b2 = ld(bih2, row) + ld(bhh2, row);
            b3 = ld(bih3, row) + ld(bhh3, row);
        }
        g_fb1[i] = b1; g_fb2[i] = b2; g_fb3[i] = b3;
    }
    for (int i = gt; i < 400 * 32; i += gs) {
        int k = i / 32, r = i % 32;
        g_WattT[i] = (r < 30) ? ld(watt, r * 400 + k) : 0.f;
    }
    for (int i = gt; i < 600 * 128; i += gs) {
        int k2 = i / 128, r = i % 128;
        float a = 0.f, b = 0.f;
        if (r < 121) { a = ld(wgmm, r * 1200 + 2 * k2); b = ld(wgmm, r * 1200 + 2 * k2 + 1); }
        g_WG2[i] = packpair(a, b);
    }
    for (int i = gt; i < 30; i += gs)  g_batt[i] = ld(batt, i);
    for (int i = gt; i < 121; i += gs) g_bgmm[i] = ld(bgmm, i);
    for (int i = gt; i < 115200; i += gs) g_inp[i] = ld(inp, i);
    for (int i = gt; i < ST_FLOATS; i += gs) g_state[i] = 0.f;
    for (int i = gt; i < 8 * 32; i += gs) g_barcnt[i] = 0u;
}

// LSTM core: 8 waves split K in k4-groups (4 k-pairs); lane = 2 rows x 8 batches.
// Per k4: 4x16B weight loads + 8 ds_read_b128 broadcasts + 64 dot2.
template<int KP2>
__device__ __forceinline__ void lstm_core(const f16x2* __restrict__ WT, const float* __restrict__ fb,
                                          float* __restrict__ cst, float* __restrict__ hdst,
                                          const f16x2* inb, float* accS, int rg, int bg, int tid)
{
    const int wv = tid >> 6, lane = tid & 63;
    const int ck4 = KP2 >> 5;                  // k4 groups per wave
    const int k40 = wv * ck4;
    const int rbase = rg * 128 + lane * 2;
    float acc[2][8];
    #pragma unroll
    for (int r = 0; r < 2; ++r)
        #pragma unroll
        for (int b = 0; b < 8; ++b) acc[r][b] = 0.f;
    const f16x2* wp = WT + (size_t)(k40 * 4) * ROWSP + rbase;
    #pragma unroll 2
    for (int k4 = 0; k4 < ck4; ++k4) {
        f16x2 wa[4], wb[4];
        #pragma unroll
        for (int j = 0; j < 4; ++j) {
            union { f16x4 v; f16x2 p[2]; } u;
            u.v = *(const f16x4*)(wp + (size_t)j * ROWSP);
            wa[j] = u.p[0]; wb[j] = u.p[1];
        }
        #pragma unroll
        for (int b = 0; b < 8; ++b) {
            union { f16x8 v; f16x2 p[4]; } h;
            h.v = *(const f16x8*)(inb + b * KP2 + (k40 + k4) * 4);
            #pragma unroll
            for (int j = 0; j < 4; ++j) {
                acc[0][b] = FDOT2(wa[j], h.p[j], acc[0][b]);
                acc[1][b] = FDOT2(wb[j], h.p[j], acc[1][b]);
            }
        }
        wp += 4 * ROWSP;
    }
    #pragma unroll
    for (int r = 0; r < 2; ++r)
        #pragma unroll
        for (int b = 0; b < 8; ++b)
            atomicAdd(&accS[(lane * 2 + r) * 9 + b], acc[r][b]);
    __syncthreads();
    if (tid < 256) {
        int bl = tid >> 5, jj = tid & 31;
        int j = rg * 32 + jj;
        if (j < 400) {
            int rl = jj * 4;
            float gi = accS[(rl + 0) * 9 + bl] + fb[rg * 128 + rl + 0];
            float gf = accS[(rl + 1) * 9 + bl] + fb[rg * 128 + rl + 1];
            float gg = accS[(rl + 2) * 9 + bl] + fb[rg * 128 + rl + 2];
            float go = accS[(rl + 3) * 9 + bl] + fb[rg * 128 + rl + 3];
            int b = bg * 8 + bl;
            float c = cst[b * 400 + j];               // owner-exclusive: plain
            float cn = sigm(gf) * c + sigm(gi) * tanhf(gg);
            cst[b * 400 + j] = cn;
            st_agent(&hdst[b * 400 + j], sigm(go) * tanhf(cn));  // cross-block: LLC
        }
    }
}

// GMM output head: 4 batches per block, transposed f16 weights, dot2.
__device__ void out_head(void* out, int tOut, int obid, int tid, char* smem)
{
    f16x2* zb = (f16x2*)smem;            // 4*600*4 = 9600
    float* zv = (float*)(smem + 9600);   // 1936
    const int pp = tOut & 1;
    const float* h1 = g_state + H1OFF + pp * (NB * NH);
    const float* h2 = g_state + H2OFF + pp * (NB * NH);
    const float* h3 = g_state + H3OFF + pp * (NB * NH);
    for (int i = tid; i < 4 * 600; i += 512) {
        int bq = i / 600, p = i % 600; int b = obid * 4 + bq;
        int kf = 2 * p;
        const float* src = (kf < 400) ? (h1 + b * 400 + kf)
                         : (kf < 800) ? (h2 + b * 400 + (kf - 400))
                                      : (h3 + b * 400 + (kf - 800));
        float2 hv = ld2_agent(src);
        zb[bq * 600 + p] = packpair(hv.x, hv.y);
    }
    __syncthreads();
    {
        int bq = tid >> 7, r = tid & 127;
        if (r < 121) {
            float acc = g_bgmm[r];
            const f16x2* zp = zb + bq * 600;
            #pragma unroll 4
            for (int k2 = 0; k2 < 600; ++k2)
                acc = FDOT2(g_WG2[k2 * 128 + r], zp[k2], acc);
            zv[bq * 121 + r] = acc;
        }
    }
    __syncthreads();
    if (tid < 484) {
        int bl = tid / 121, jo = tid - bl * 121;
        const float* z = zv + bl * 121;
        float val;
        if (jo < 20) {
            float m = -1e30f;
            for (int i = 0; i < 20; ++i) m = fmaxf(m, z[1 + i]);
            float s = 0.f;
            for (int i = 0; i < 20; ++i) s += expf(z[1 + i] - m);
            val = expf(z[1 + jo] - m) / s;
        } else if (jo < 60)  val = z[jo + 1];
        else if (jo < 100)   val = expf(z[jo + 1]);
        else if (jo < 120)   val = tanhf(z[jo + 1]);
        else                 val = 1.f / (1.f + expf(-z[0]));
        int idx = ((obid * 4 + bl) * NT + tOut) * NOUT + jo;
        if (g_isf32) ((float*)out)[idx] = val;
        else         ((u16*)out)[idx]  = f2bf(val);
    }
    __syncthreads();
}

__device__ void phaseA_lstm1(int t, int cur, int prev, int rg, int bg, int tid, char* smem)
{
    f16x2* inb = (f16x2*)smem;             // 8192
    float* accS = (float*)(smem + 8192);   // 4608
    const float* h1p = g_state + H1OFF + prev * (NB * NH);
    for (int i = tid; i < 8 * 256; i += 512) {
        int bl = i >> 8, p = i & 255; int b = bg * 8 + bl;
        float a = 0.f, v = 0.f;
        if (p < 200)      { float2 hv = ld2_agent(h1p + b * 400 + 2 * p); a = hv.x; v = hv.y; }
        else if (p < 230) { int q = p - 200;
                            float2 wv = ld2_agent(g_state + WINOFF + b * 60 + 2 * q);
                            a = wv.x; v = wv.y; }
        else if (p == 230){ a = g_inp[(b * NT + t) * 3 + 0]; v = g_inp[(b * NT + t) * 3 + 1]; }
        else if (p == 231){ a = g_inp[(b * NT + t) * 3 + 2]; }
        inb[bl * 256 + p] = packpair(a, v);
    }
    for (int i = tid; i < 1152; i += 512) accS[i] = 0.f;
    __syncthreads();
    lstm_core<256>(g_WT1, g_fb1, g_state + C1OFF, g_state + H1OFF + cur * (NB * NH),
                   inb, accS, rg, bg, tid);
}

__device__ void phaseB_att_lstm2(const int* __restrict__ cseq, const int* __restrict__ clen,
                                 int t, int cur, int prev, int rg, int bg, int tid, char* smem)
{
    f16x2* inb  = (f16x2*)smem;              // 14336
    float* h1f  = (float*)(smem + 14336);    // 12800
    float* accS = (float*)(smem + 27136);    // 4608
    float* ab   = (float*)(smem + 31744);    // 960
    float* phi  = (float*)(smem + 32704);    // 1600
    float* kap  = (float*)(smem + 34304);    // 320
    int*   chs  = (int*)  (smem + 34624);    // 1600
    int*   len  = (int*)  (smem + 36224);    // 32
    const float* h1  = g_state + H1OFF + cur  * (NB * NH);
    const float* h2p = g_state + H2OFF + prev * (NB * NH);
    for (int i = tid; i < 8 * 448; i += 512) {
        int bl = i / 448, p = i % 448; int b = bg * 8 + bl;
        float a = 0.f, v = 0.f;
        if (p < 200) {
            float2 hv = ld2_agent(h1 + b * 400 + 2 * p); a = hv.x; v = hv.y;
            h1f[bl * 400 + 2 * p] = a; h1f[bl * 400 + 2 * p + 1] = v;
        }
        else if (p < 400) { int q = p - 200;
                            float2 hv = ld2_agent(h2p + b * 400 + 2 * q); a = hv.x; v = hv.y; }
        else if (p == 430){ a = g_inp[(b * NT + t) * 3 + 0]; v = g_inp[(b * NT + t) * 3 + 1]; }
        else if (p == 431){ a = g_inp[(b * NT + t) * 3 + 2]; }
        inb[bl * 448 + p] = packpair(a, v);
    }
    for (int i = tid; i < 1152; i += 512) accS[i] = 0.f;
    if (tid < 80) { int bl = tid / 10, k = tid % 10;
        kap[tid] = ld_agent(g_state + KPOFF + prev * (NB * NKATT) + (bg * 8 + bl) * 10 + k); }
    else if (tid >= 80 && tid < 480) { int i = tid - 80; int bl = i / 50, u = i % 50;
        chs[bl * 50 + u] = cseq[(bg * 8 + bl) * NTC + u]; }
    else if (tid >= 480 && tid < 488) len[tid - 480] = clen[bg * 8 + (tid - 480)];
    __syncthreads();
    if (tid < 240) {                       // p = exp(h1 @ W_att.T + b_att)
        int bl = tid / 30, rr = tid % 30;
        float acc = g_batt[rr];
        const float* hp = h1f + bl * 400;
        #pragma unroll 4
        for (int k = 0; k < 400; ++k) acc += g_WattT[k * 32 + rr] * hp[k];
        ab[bl * 30 + rr] = expf(acc);
    }
    __syncthreads();
    if (tid < 400) {                       // phi (length-masked)
        int bl = tid / 50, u = tid % 50;
        float ph = 0.f;
        if (u < len[bl]) {
            float uf = (float)u;
            for (int k = 0; k < 10; ++k) {
                float kn = kap[bl * 10 + k] + ab[bl * 30 + 20 + k];
                float d = kn - uf;
                ph += ab[bl * 30 + k] * expf(-ab[bl * 30 + 10 + k] * d * d);
            }
        }
        phi[bl * 50 + u] = ph;
    } else if (tid >= 400 && tid < 480 && rg == 0) {   // kappa writer
        int i = tid - 400; int bl = i / 10, k = i % 10;
        st_agent(g_state + KPOFF + cur * (NB * NKATT) + (bg * 8 + bl) * 10 + k,
                 kap[bl * 10 + k] + ab[bl * 30 + 20 + k]);
    }
    __syncthreads();
    if (tid < 240) {                       // window pairs -> inb + g_state
        int bl = tid / 30, q = tid % 30;
        int a0 = 2 * q, a1 = 2 * q + 1;
        float w0 = 0.f, w1 = 0.f;
        for (int u = 0; u < NTC; ++u) {
            float pv = phi[bl * 50 + u]; int cc = chs[bl * 50 + u];
            if (cc == a0) w0 += pv;
            if (cc == a1) w1 += pv;
        }
        inb[bl * 448 + 400 + q] = packpair(w0, w1);
        if (rg == 0) { int b = bg * 8 + bl;
            st_agent(g_state + WINOFF + b * 60 + a0, w0);
            st_agent(g_state + WINOFF + b * 60 + a1, w1); }
    }
    __syncthreads();
    lstm_core<448>(g_WT2, g_fb2, g_state + C2OFF, g_state + H2OFF + cur * (NB * NH),
                   inb, accS, rg, bg, tid);
}

__device__ void phaseC_lstm3(int t, int cur, int prev, int rg, int bg, int tid, char* smem)
{
    f16x2* inb  = (f16x2*)smem;              // 20480
    float* accS = (float*)(smem + 20480);    // 4608
    const float* h1  = g_state + H1OFF + cur  * (NB * NH);
    const float* h2  = g_state + H2OFF + cur  * (NB * NH);
    const float* h3p = g_state + H3OFF + prev * (NB * NH);
    for (int i = tid; i < 8 * 640; i += 512) {
        int bl = i / 640, p = i % 640; int b = bg * 8 + bl;
        float a = 0.f, v = 0.f;
        if (p < 200)      { float2 hv = ld2_agent(h1 + b * 400 + 2 * p); a = hv.x; v = hv.y; }
        else if (p < 400) { int q = p - 200; float2 hv = ld2_agent(h2 + b * 400 + 2 * q); a = hv.x; v = hv.y; }
        else if (p < 600) { int q = p - 400; float2 hv = ld2_agent(h3p + b * 400 + 2 * q); a = hv.x; v = hv.y; }
        else if (p < 630) { int q = p - 600;
                            float2 wv = ld2_agent(g_state + WINOFF + b * 60 + 2 * q);
                            a = wv.x; v = wv.y; }
        else if (p == 630){ a = g_inp[(b * NT + t) * 3 + 0]; v = g_inp[(b * NT + t) * 3 + 1]; }
        else if (p == 631){ a = g_inp[(b * NT + t) * 3 + 2]; }
        inb[bl * 640 + p] = packpair(a, v);
    }
    for (int i = tid; i < 1152; i += 512) accS[i] = 0.f;
    __syncthreads();
    lstm_core<640>(g_WT3, g_fb3, g_state + C3OFF, g_state + H3OFF + cur * (NB * NH),
                   inb, accS, rg, bg, tid);
}

// Persistent kernel with XCD-affinity swizzle (XCD heuristic: bid % 8).
// slot s = bid>>3, x = bid&7:
//   s<8      : LSTM rg=x      bg=s        (rg slices 0..7 pinned to XCD x)
//   s in 8..12: q=5x+s-8; LSTM rg=8+q/8 bg=q%8  (rg 8..12 on <=2 XCDs each)
//   s=13,14  : head obid=2x+(s-13), bg=x
__global__ __launch_bounds__(512) void k_persist(void* out,
                                                 const int* __restrict__ cseq,
                                                 const int* __restrict__ clen)
{
    __shared__ __align__(16) char smem[36352];
    const int tid = threadIdx.x;
    const int bid = blockIdx.x;
    const int x = bid & 7, s = bid >> 3;
    bool isL; int rg = 0, bg, obid = 0;
    if (s < 8)       { isL = true;  rg = x; bg = s; }
    else if (s < 13) { isL = true;  int q = 5 * x + (s - 8); rg = 8 + (q >> 3); bg = q & 7; }
    else             { isL = false; obid = 2 * x + (s - 13); bg = x; }
    unsigned bars = 0;
    for (int t = 0; t < NT; ++t) {
        const int cur = t & 1, prev = cur ^ 1;
        // Phase A: LSTM1 + GMM head for t-1
        if (isL)          phaseA_lstm1(t, cur, prev, rg, bg, tid, smem);
        else if (t > 0)   out_head(out, t - 1, obid, tid, smem);
        bg_barrier(bg, &bars);
        // Phase B: attention (per-block recompute) + LSTM2
        if (isL)          phaseB_att_lstm2(cseq, clen, t, cur, prev, rg, bg, tid, smem);
        bg_barrier(bg, &bars);
        // Phase C: LSTM3
        if (isL)          phaseC_lstm3(t, cur, prev, rg, bg, tid, smem);
        bg_barrier(bg, &bars);
    }
    if (!isL) out_head(out, NT - 1, obid, tid, smem);
}

extern "C" void kernel_launch(void* const* d_in, const int* in_sizes, int n_in,
                              void* d_out, int out_size, void* d_ws, size_t ws_size,
                              hipStream_t stream)
{
    hipLaunchKernelGGL(k_detect, dim3(1), dim3(64), 0, stream, d_in[5]);  // W_hh1
    hipLaunchKernelGGL(k_convert, dim3(2048), dim3(256), 0, stream,
                       d_in[0],
                       d_in[3], d_in[4], d_in[5], d_in[6],
                       d_in[7], d_in[8], d_in[9], d_in[10],
                       d_in[11], d_in[12], d_in[13], d_in[14],
                       d_in[15], d_in[16], d_in[17], d_in[18]);
    void* outp = d_out;
    const int* cseq = (const int*)d_in[1];
    const int* clen = (const int*)d_in[2];
    void* args[] = { (void*)&outp, (void*)&cseq, (void*)&clen };
    hipLaunchCooperativeKernel((void*)k_persist, dim3(120), dim3(512), args, 0, stream);
}

// Round 7
// 50587.366 us; speedup vs baseline: 1.8548x; 1.1754x over previous
//
#include <hip/hip_runtime.h>
#include <hip/hip_bf16.h>

#define NB 64
#define NT 600
#define NTC 50
#define NH 400
#define NKATT 10
#define NALPHA 60
#define NOUT 121

typedef unsigned short u16;
typedef _Float16 f16x2 __attribute__((ext_vector_type(2)));
typedef _Float16 f16x4 __attribute__((ext_vector_type(4)));
typedef _Float16 f16x8 __attribute__((ext_vector_type(8)));

#if defined(__has_builtin)
#if __has_builtin(__builtin_amdgcn_fdot2)
#define FDOT2(a,b,c) __builtin_amdgcn_fdot2((a),(b),(c),false)
#endif
#endif
#ifndef FDOT2
#define FDOT2(a,b,c) ((c) + (float)(a)[0]*(float)(b)[0] + (float)(a)[1]*(float)(b)[1])
#endif

// Padded fused-K sizes (pairs): K1=512->256, K2=896->448, K3=1280->640. Rows padded 1600->1664.
#define ROWSP 1664
#define GRPB 15            // blocks per batch-group barrier: 13 LSTM + 2 head

// state layout (floats)
#define H1OFF 0            // [2][NB][NH] ping-pong
#define H2OFF 51200
#define H3OFF 102400
#define C1OFF 153600
#define C2OFF 179200
#define C3OFF 204800
#define KPOFF 230400       // [2][NB][NKATT]
#define WINOFF 231680      // [NB][NALPHA]
#define ST_FLOATS 235520

__device__ __align__(16) f16x2 g_WT1[256 * ROWSP];
__device__ __align__(16) f16x2 g_WT2[448 * ROWSP];
__device__ __align__(16) f16x2 g_WT3[640 * ROWSP];
__device__ __align__(16) f16x2 g_WG2[600 * 128];
__device__ __align__(16) float g_fb1[ROWSP], g_fb2[ROWSP], g_fb3[ROWSP];
__device__ __align__(16) float g_WattT[400 * 32];
__device__ float g_batt[30], g_bgmm[121];
__device__ __align__(16) float g_inp[115200];
__device__ float g_state[ST_FLOATS];
__device__ unsigned int g_barcnt[8 * 32];   // one cacheline per batch-group
__device__ int   g_isf32;

__device__ __forceinline__ float bf2f(u16 v) {
    union { unsigned int u; float f; } t; t.u = ((unsigned int)v) << 16; return t.f;
}
__device__ __forceinline__ u16 f2bf(float f) {
    union { float ff; unsigned int u; } t; t.ff = f;
    unsigned int lsb = (t.u >> 16) & 1u;
    t.u += 0x7fffu + lsb;
    return (u16)(t.u >> 16);
}
__device__ __forceinline__ float sigm(float x) { return 1.f / (1.f + expf(-x)); }
__device__ __forceinline__ f16x2 packpair(float a, float b) {
    f16x2 r; r[0] = (_Float16)a; r[1] = (_Float16)b; return r;
}

// ---- agent-scope (cross-XCD coherent, LLC-direct) state accessors ----
__device__ __forceinline__ float ld_agent(const float* p) {
    return __hip_atomic_load(p, __ATOMIC_RELAXED, __HIP_MEMORY_SCOPE_AGENT);
}
__device__ __forceinline__ void st_agent(float* p, float v) {
    __hip_atomic_store(p, v, __ATOMIC_RELAXED, __HIP_MEMORY_SCOPE_AGENT);
}
__device__ __forceinline__ float2 ld2_agent(const float* p) {
    unsigned long long u = __hip_atomic_load((const unsigned long long*)p,
                                             __ATOMIC_RELAXED, __HIP_MEMORY_SCOPE_AGENT);
    union { unsigned long long u; float2 f; } t; t.u = u; return t.f;
}

// Split barrier: arrive (syncthreads drains vmcnt -> stores at LLC; tid0 bumps counter),
// wait (tid0 spins; syncthreads releases). Between arrive and wait: stage OLD data only.
__device__ __forceinline__ void bar_arrive(int bg, unsigned* bars) {
    __syncthreads();
    ++(*bars);
    if (threadIdx.x == 0)
        __hip_atomic_fetch_add(&g_barcnt[bg * 32], 1u, __ATOMIC_RELAXED, __HIP_MEMORY_SCOPE_AGENT);
}
__device__ __forceinline__ void bar_wait(int bg, unsigned bars) {
    if (threadIdx.x == 0) {
        unsigned tgt = (unsigned)GRPB * bars;
        while (__hip_atomic_load(&g_barcnt[bg * 32], __ATOMIC_RELAXED, __HIP_MEMORY_SCOPE_AGENT) < tgt)
            __builtin_amdgcn_s_sleep(1);
    }
    __syncthreads();
}

__global__ void k_detect(const void* whh1) {
    if (threadIdx.x == 0 && blockIdx.x == 0) {
        const u16* p = (const u16*)whh1;
        int f32 = 0;
        for (int k = 0; k < 256; ++k) {
            float v = bf2f(p[2 * k]);
            if (!(fabsf(v) < 1e3f)) f32 = 1;
        }
        g_isf32 = f32;
    }
}

// Build fused/transposed/permuted f16 weights + biases; canonicalize inputs; zero state.
__global__ void k_convert(const void* inp,
                          const void* wih1, const void* bih1, const void* whh1, const void* bhh1,
                          const void* wih2, const void* bih2, const void* whh2, const void* bhh2,
                          const void* wih3, const void* bih3, const void* whh3, const void* bhh3,
                          const void* watt, const void* batt, const void* wgmm, const void* bgmm)
{
    const int gt = blockIdx.x * blockDim.x + threadIdx.x;
    const int gs = gridDim.x * blockDim.x;
    const int f32 = g_isf32;
    auto ld = [f32](const void* p, int i) -> float {
        return f32 ? ((const float*)p)[i] : bf2f(((const u16*)p)[i]);
    };
    auto w1col = [&](int kf, int row) -> float {
        if (kf < 400) return ld(whh1, row * 400 + kf);
        if (kf < 460) return ld(wih1, row * 63 + (kf - 400));
        if (kf < 463) return ld(wih1, row * 63 + 60 + (kf - 460));
        return 0.f;
    };
    auto w2col = [&](int kf, int row) -> float {
        if (kf < 400) return ld(wih2, row * 463 + 3 + kf);
        if (kf < 800) return ld(whh2, row * 400 + (kf - 400));
        if (kf < 860) return ld(wih2, row * 463 + 403 + (kf - 800));
        if (kf < 863) return ld(wih2, row * 463 + (kf - 860));
        return 0.f;
    };
    auto w3col = [&](int kf, int row) -> float {
        if (kf < 400)  return ld(wih3, row * 863 + 3 + kf);
        if (kf < 800)  return ld(wih3, row * 863 + 403 + (kf - 400));
        if (kf < 1200) return ld(whh3, row * 400 + (kf - 800));
        if (kf < 1260) return ld(wih3, row * 863 + 803 + (kf - 1200));
        if (kf < 1263) return ld(wih3, row * 863 + (kf - 1260));
        return 0.f;
    };
    for (int i = gt; i < 256 * ROWSP; i += gs) {
        int k2 = i / ROWSP, rp = i % ROWSP;
        int j = rp >> 2, g = rp & 3;
        float a = 0.f, b = 0.f;
        if (j < 400) { int row = g * 400 + j; a = w1col(2 * k2, row); b = w1col(2 * k2 + 1, row); }
        g_WT1[i] = packpair(a, b);
    }
    for (int i = gt; i < 448 * ROWSP; i += gs) {
        int k2 = i / ROWSP, rp = i % ROWSP;
        int j = rp >> 2, g = rp & 3;
        float a = 0.f, b = 0.f;
        if (j < 400) { int row = g * 400 + j; a = w2col(2 * k2, row); b = w2col(2 * k2 + 1, row); }
        g_WT2[i] = packpair(a, b);
    }
    for (int i = gt; i < 640 * ROWSP; i += gs) {
        int k2 = i / ROWSP, rp = i % ROWSP;
        int j = rp >> 2, g = rp & 3;
        float a = 0.f, b = 0.f;
        if (j < 400) { int row = g * 400 + j; a = w3col(2 * k2, row); b = w3col(2 * k2 + 1, row); }
        g_WT3[i] = packpair(a, b);
    }
    for (int i = gt; i < ROWSP; i += gs) {
        int j = i >> 2, g = i & 3;
        float b1 = 0.f, b2 = 0.f, b3 = 0.f;
        if (j < 400) {
            int row = g * 400 + j;
            b1 = ld(bih1, row) + ld(bhh1, row);
            b2 = ld(bih2, row) + ld(bhh2, row);
            b3 = ld(bih3, row) + ld(bhh3, row);
        }
        g_fb1[i] = b1; g_fb2[i] = b2; g_fb3[i] = b3;
    }
    for (int i = gt; i < 400 * 32; i += gs) {
        int k = i / 32, r = i % 32;
        g_WattT[i] = (r < 30) ? ld(watt, r * 400 + k) : 0.f;
    }
    for (int i = gt; i < 600 * 128; i += gs) {
        int k2 = i / 128, r = i % 128;
        float a = 0.f, b = 0.f;
        if (r < 121) { a = ld(wgmm, r * 1200 + 2 * k2); b = ld(wgmm, r * 1200 + 2 * k2 + 1); }
        g_WG2[i] = packpair(a, b);
    }
    for (int i = gt; i < 30; i += gs)  g_batt[i] = ld(batt, i);
    for (int i = gt; i < 121; i += gs) g_bgmm[i] = ld(bgmm, i);
    for (int i = gt; i < 115200; i += gs) g_inp[i] = ld(inp, i);
    for (int i = gt; i < ST_FLOATS; i += gs) g_state[i] = 0.f;
    for (int i = gt; i < 8 * 32; i += gs) g_barcnt[i] = 0u;
}

// LSTM core: 8 waves split K in k4-groups; lane = 2 rowpairs x 8 batches.
template<int KP2>
__device__ __forceinline__ void lstm_core(const f16x2* __restrict__ WT, const float* __restrict__ fb,
                                          float* __restrict__ cst, float* __restrict__ hdst,
                                          const f16x2* inb, float* accS, int rg, int bg, int tid)
{
    const int wv = tid >> 6, lane = tid & 63;
    const int ck4 = KP2 >> 5;
    const int k40 = wv * ck4;
    const int rbase = rg * 128 + lane * 2;
    float acc[2][8];
    #pragma unroll
    for (int r = 0; r < 2; ++r)
        #pragma unroll
        for (int b = 0; b < 8; ++b) acc[r][b] = 0.f;
    const f16x2* wp = WT + (size_t)(k40 * 4) * ROWSP + rbase;
    #pragma unroll 2
    for (int k4 = 0; k4 < ck4; ++k4) {
        f16x2 wa[4], wb[4];
        #pragma unroll
        for (int j = 0; j < 4; ++j) {
            union { f16x4 v; f16x2 p[2]; } u;
            u.v = *(const f16x4*)(wp + (size_t)j * ROWSP);
            wa[j] = u.p[0]; wb[j] = u.p[1];
        }
        #pragma unroll
        for (int b = 0; b < 8; ++b) {
            union { f16x8 v; f16x2 p[4]; } h;
            h.v = *(const f16x8*)(inb + b * KP2 + (k40 + k4) * 4);
            #pragma unroll
            for (int j = 0; j < 4; ++j) {
                acc[0][b] = FDOT2(wa[j], h.p[j], acc[0][b]);
                acc[1][b] = FDOT2(wb[j], h.p[j], acc[1][b]);
            }
        }
        wp += 4 * ROWSP;
    }
    #pragma unroll
    for (int r = 0; r < 2; ++r)
        #pragma unroll
        for (int b = 0; b < 8; ++b)
            atomicAdd(&accS[(lane * 2 + r) * 9 + b], acc[r][b]);
    __syncthreads();
    if (tid < 256) {
        int bl = tid >> 5, jj = tid & 31;
        int j = rg * 32 + jj;
        if (j < 400) {
            int rl = jj * 4;
            float gi = accS[(rl + 0) * 9 + bl] + fb[rg * 128 + rl + 0];
            float gf = accS[(rl + 1) * 9 + bl] + fb[rg * 128 + rl + 1];
            float gg = accS[(rl + 2) * 9 + bl] + fb[rg * 128 + rl + 2];
            float go = accS[(rl + 3) * 9 + bl] + fb[rg * 128 + rl + 3];
            int b = bg * 8 + bl;
            float c = cst[b * 400 + j];               // owner-exclusive: plain
            float cn = sigm(gf) * c + sigm(gi) * tanhf(gg);
            cst[b * 400 + j] = cn;
            st_agent(&hdst[b * 400 + j], sigm(go) * tanhf(cn));  // cross-block: LLC
        }
    }
}

// GMM output head: 4 batches per block, transposed f16 weights, 4-way split acc chain.
__device__ void out_head(void* out, int tOut, int obid, int tid, char* smem)
{
    f16x2* zb = (f16x2*)smem;            // 9600
    float* zv = (float*)(smem + 9600);   // 1936
    const int pp = tOut & 1;
    const float* h1 = g_state + H1OFF + pp * (NB * NH);
    const float* h2 = g_state + H2OFF + pp * (NB * NH);
    const float* h3 = g_state + H3OFF + pp * (NB * NH);
    for (int i = tid; i < 4 * 600; i += 512) {
        int bq = i / 600, p = i % 600; int b = obid * 4 + bq;
        int kf = 2 * p;
        const float* src = (kf < 400) ? (h1 + b * 400 + kf)
                         : (kf < 800) ? (h2 + b * 400 + (kf - 400))
                                      : (h3 + b * 400 + (kf - 800));
        float2 hv = ld2_agent(src);
        zb[bq * 600 + p] = packpair(hv.x, hv.y);
    }
    __syncthreads();
    {
        int bq = tid >> 7, r = tid & 127;
        if (r < 121) {
            float ac0 = g_bgmm[r], ac1 = 0.f, ac2 = 0.f, ac3 = 0.f;
            const f16x2* zp = zb + bq * 600;
            #pragma unroll 2
            for (int k2 = 0; k2 < 600; k2 += 4) {
                ac0 = FDOT2(g_WG2[(k2 + 0) * 128 + r], zp[k2 + 0], ac0);
                ac1 = FDOT2(g_WG2[(k2 + 1) * 128 + r], zp[k2 + 1], ac1);
                ac2 = FDOT2(g_WG2[(k2 + 2) * 128 + r], zp[k2 + 2], ac2);
                ac3 = FDOT2(g_WG2[(k2 + 3) * 128 + r], zp[k2 + 3], ac3);
            }
            zv[bq * 121 + r] = (ac0 + ac1) + (ac2 + ac3);
        }
    }
    __syncthreads();
    if (tid < 484) {
        int bl = tid / 121, jo = tid - bl * 121;
        const float* z = zv + bl * 121;
        float val;
        if (jo < 20) {
            float m = -1e30f;
            for (int i = 0; i < 20; ++i) m = fmaxf(m, z[1 + i]);
            float s = 0.f;
            for (int i = 0; i < 20; ++i) s += expf(z[1 + i] - m);
            val = expf(z[1 + jo] - m) / s;
        } else if (jo < 60)  val = z[jo + 1];
        else if (jo < 100)   val = expf(z[jo + 1]);
        else if (jo < 120)   val = tanhf(z[jo + 1]);
        else                 val = 1.f / (1.f + expf(-z[0]));
        int idx = ((obid * 4 + bl) * NT + tOut) * NOUT + jo;
        if (g_isf32) ((float*)out)[idx] = val;
        else         ((u16*)out)[idx]  = f2bf(val);
    }
    __syncthreads();
}

// Phase A: LSTM1, inputs h1[prev]+win(t-1)+x — all published >=1 barrier ago.
__device__ void phaseA_lstm1(int t, int cur, int prev, int rg, int bg, int tid, char* smem)
{
    f16x2* inb = (f16x2*)smem;             // 8192
    float* accS = (float*)(smem + 8192);   // 4608
    const float* h1p = g_state + H1OFF + prev * (NB * NH);
    for (int i = tid; i < 8 * 256; i += 512) {
        int bl = i >> 8, p = i & 255; int b = bg * 8 + bl;
        float a = 0.f, v = 0.f;
        if (p < 200)      { float2 hv = ld2_agent(h1p + b * 400 + 2 * p); a = hv.x; v = hv.y; }
        else if (p < 230) { int q = p - 200;
                            float2 wv = ld2_agent(g_state + WINOFF + b * 60 + 2 * q);
                            a = wv.x; v = wv.y; }
        else if (p == 230){ a = g_inp[(b * NT + t) * 3 + 0]; v = g_inp[(b * NT + t) * 3 + 1]; }
        else if (p == 231){ a = g_inp[(b * NT + t) * 3 + 2]; }
        inb[bl * 256 + p] = packpair(a, v);
    }
    for (int i = tid; i < 1152; i += 512) accS[i] = 0.f;
    __syncthreads();
    lstm_core<256>(g_WT1, g_fb1, g_state + C1OFF, g_state + H1OFF + cur * (NB * NH),
                   inb, accS, rg, bg, tid);
}

// Phase B early (between barA.arrive and barA.wait): stage OLD data only.
__device__ void pB_early(const int* __restrict__ cseq, const int* __restrict__ clen,
                         int t, int prev, int bg, int tid, char* smem)
{
    f16x2* inb  = (f16x2*)smem;
    float* accS = (float*)(smem + 27136);
    float* kap  = (float*)(smem + 34304);
    int*   chs  = (int*)  (smem + 34624);
    int*   len  = (int*)  (smem + 36224);
    const float* h2p = g_state + H2OFF + prev * (NB * NH);
    for (int i = tid; i < 8 * 248; i += 512) {
        int bl = i / 248, p = 200 + i % 248; int b = bg * 8 + bl;
        float a = 0.f, v = 0.f;
        if (p < 400)      { int q = p - 200; float2 hv = ld2_agent(h2p + b * 400 + 2 * q); a = hv.x; v = hv.y; }
        else if (p == 430){ a = g_inp[(b * NT + t) * 3 + 0]; v = g_inp[(b * NT + t) * 3 + 1]; }
        else if (p == 431){ a = g_inp[(b * NT + t) * 3 + 2]; }
        if (p < 400 || p >= 430)                       // [400,430) = window, filled in late
            inb[bl * 448 + p] = packpair(a, v);
    }
    for (int i = tid; i < 1152; i += 512) accS[i] = 0.f;
    if (tid < 80) { int bl = tid / 10, k = tid % 10;
        kap[tid] = ld_agent(g_state + KPOFF + prev * (NB * NKATT) + (bg * 8 + bl) * 10 + k); }
    else if (tid >= 80 && tid < 480) { int i = tid - 80; int bl = i / 50, u = i % 50;
        chs[bl * 50 + u] = cseq[(bg * 8 + bl) * NTC + u]; }
    else if (tid >= 480 && tid < 488) len[tid - 480] = clen[bg * 8 + (tid - 480)];
}

// Phase B late (after barA.wait): h1-dependent staging + attention + LSTM2.
__device__ void pB_late(int t, int cur, int rg, int bg, int tid, char* smem)
{
    f16x2* inb  = (f16x2*)smem;
    float* h1f  = (float*)(smem + 14336);
    float* accS = (float*)(smem + 27136);
    float* ab   = (float*)(smem + 31744);
    float* phi  = (float*)(smem + 32704);
    float* kap  = (float*)(smem + 34304);
    int*   chs  = (int*)  (smem + 34624);
    int*   len  = (int*)  (smem + 36224);
    const float* h1 = g_state + H1OFF + cur * (NB * NH);
    for (int i = tid; i < 8 * 200; i += 512) {
        int bl = i / 200, p = i % 200; int b = bg * 8 + bl;
        float2 hv = ld2_agent(h1 + b * 400 + 2 * p);
        h1f[bl * 400 + 2 * p] = hv.x; h1f[bl * 400 + 2 * p + 1] = hv.y;
        inb[bl * 448 + p] = packpair(hv.x, hv.y);
    }
    __syncthreads();
    if (tid < 240) {                       // p = exp(h1 @ W_att.T + b_att)
        int bl = tid / 30, rr = tid % 30;
        float acc = g_batt[rr];
        const float* hp = h1f + bl * 400;
        #pragma unroll 4
        for (int k = 0; k < 400; ++k) acc += g_WattT[k * 32 + rr] * hp[k];
        ab[bl * 30 + rr] = expf(acc);
    }
    __syncthreads();
    if (tid < 400) {                       // phi (length-masked)
        int bl = tid / 50, u = tid % 50;
        float ph = 0.f;
        if (u < len[bl]) {
            float uf = (float)u;
            for (int k = 0; k < 10; ++k) {
                float kn = kap[bl * 10 + k] + ab[bl * 30 + 20 + k];
                float d = kn - uf;
                ph += ab[bl * 30 + k] * expf(-ab[bl * 30 + 10 + k] * d * d);
            }
        }
        phi[bl * 50 + u] = ph;
    } else if (tid >= 400 && tid < 480 && rg == 0) {   // kappa writer
        int i = tid - 400; int bl = i / 10, k = i % 10;
        st_agent(g_state + KPOFF + cur * (NB * NKATT) + (bg * 8 + bl) * 10 + k,
                 kap[bl * 10 + k] + ab[bl * 30 + 20 + k]);
    }
    __syncthreads();
    if (tid < 240) {                       // window pairs -> inb + g_state
        int bl = tid / 30, q = tid % 30;
        int a0 = 2 * q, a1 = 2 * q + 1;
        float w0 = 0.f, w1 = 0.f;
        for (int u = 0; u < NTC; ++u) {
            float pv = phi[bl * 50 + u]; int cc = chs[bl * 50 + u];
            if (cc == a0) w0 += pv;
            if (cc == a1) w1 += pv;
        }
        inb[bl * 448 + 400 + q] = packpair(w0, w1);
        if (rg == 0) { int b = bg * 8 + bl;
            st_agent(g_state + WINOFF + b * 60 + a0, w0);
            st_agent(g_state + WINOFF + b * 60 + a1, w1); }
    }
    __syncthreads();
    lstm_core<448>(g_WT2, g_fb2, g_state + C2OFF, g_state + H2OFF + cur * (NB * NH),
                   inb, accS, rg, bg, tid);
}

// Phase C early (between barB.arrive and barB.wait): h1 (ready since barA), h3p, x.
__device__ void pC_early(int t, int cur, int prev, int bg, int tid, char* smem)
{
    f16x2* inb  = (f16x2*)smem;
    float* accS = (float*)(smem + 20480);
    const float* h1  = g_state + H1OFF + cur  * (NB * NH);
    const float* h3p = g_state + H3OFF + prev * (NB * NH);
    for (int i = tid; i < 8 * 440; i += 512) {
        int bl = i / 440, j = i % 440; int b = bg * 8 + bl;
        int p; float a = 0.f, v = 0.f; bool wr = true;
        if (j < 200) { p = j; float2 hv = ld2_agent(h1 + b * 400 + 2 * p); a = hv.x; v = hv.y; }
        else {
            p = j + 200;                                    // p in [400,640)
            if (p < 600)      { int q = p - 400; float2 hv = ld2_agent(h3p + b * 400 + 2 * q); a = hv.x; v = hv.y; }
            else if (p == 630){ a = g_inp[(b * NT + t) * 3 + 0]; v = g_inp[(b * NT + t) * 3 + 1]; }
            else if (p == 631){ a = g_inp[(b * NT + t) * 3 + 2]; }
            else if (p < 630) wr = false;                   // [600,630) = win, staged late
        }
        if (wr) inb[bl * 640 + p] = packpair(a, v);
    }
    for (int i = tid; i < 1152; i += 512) accS[i] = 0.f;
}

// Phase C late (after barB.wait): h2 + win staging, then LSTM3.
__device__ void pC_late(int cur, int rg, int bg, int tid, char* smem)
{
    f16x2* inb  = (f16x2*)smem;
    float* accS = (float*)(smem + 20480);
    const float* h2 = g_state + H2OFF + cur * (NB * NH);
    for (int i = tid; i < 8 * 230; i += 512) {
        int bl = i / 230, j = i % 230; int b = bg * 8 + bl;
        float a, v; int p;
        if (j < 200) { p = 200 + j; int q = j;
                       float2 hv = ld2_agent(h2 + b * 400 + 2 * q); a = hv.x; v = hv.y; }
        else         { p = 600 + (j - 200); int q = j - 200;
                       float2 wv = ld2_agent(g_state + WINOFF + b * 60 + 2 * q); a = wv.x; v = wv.y; }
        inb[bl * 640 + p] = packpair(a, v);
    }
    __syncthreads();
    lstm_core<640>(g_WT3, g_fb3, g_state + C3OFF, g_state + H3OFF + cur * (NB * NH),
                   inb, accS, rg, bg, tid);
    __syncthreads();   // LDS reuse guard before next phase A
}

// Persistent kernel, XCD-affinity swizzle (XCD = bid%8). 2 barriers/step + 1 final.
__global__ __launch_bounds__(512) void k_persist(void* out,
                                                 const int* __restrict__ cseq,
                                                 const int* __restrict__ clen)
{
    __shared__ __align__(16) char smem[36352];
    const int tid = threadIdx.x;
    const int bid = blockIdx.x;
    const int x = bid & 7, s = bid >> 3;
    bool isL; int rg = 0, bg, obid = 0;
    if (s < 8)       { isL = true;  rg = x; bg = s; }
    else if (s < 13) { isL = true;  int q = 5 * x + (s - 8); rg = 8 + (q >> 3); bg = q & 7; }
    else             { isL = false; obid = 2 * x + (s - 13); bg = x; }
    unsigned bars = 0;
    for (int t = 0; t < NT; ++t) {
        const int cur = t & 1, prev = cur ^ 1;
        if (isL) phaseA_lstm1(t, cur, prev, rg, bg, tid, smem);
        bar_arrive(bg, &bars);                      // barA: publishes h1(t)
        if (isL) pB_early(cseq, clen, t, prev, bg, tid, smem);
        bar_wait(bg, bars);
        if (isL)        pB_late(t, cur, rg, bg, tid, smem);
        else if (t > 0) out_head(out, t - 1, obid, tid, smem);   // h3(t-1) gated by barA
        bar_arrive(bg, &bars);                      // barB: publishes h2(t), win(t)
        if (isL) pC_early(t, cur, prev, bg, tid, smem);
        bar_wait(bg, bars);
        if (isL) pC_late(cur, rg, bg, tid, smem);
        // no barrier after C: next-step A reads only h1/win (already gated);
        // h3 consumers (C(t+1), out_head(t)) are gated by the next barriers.
    }
    bar_arrive(bg, &bars);                          // final: publish h3(NT-1)
    bar_wait(bg, bars);
    if (!isL) out_head(out, NT - 1, obid, tid, smem);
}

extern "C" void kernel_launch(void* const* d_in, const int* in_sizes, int n_in,
                              void* d_out, int out_size, void* d_ws, size_t ws_size,
                              hipStream_t stream)
{
    hipLaunchKernelGGL(k_detect, dim3(1), dim3(64), 0, stream, d_in[5]);  // W_hh1
    hipLaunchKernelGGL(k_convert, dim3(2048), dim3(256), 0, stream,
                       d_in[0],
                       d_in[3], d_in[4], d_in[5], d_in[6],
                       d_in[7], d_in[8], d_in[9], d_in[10],
                       d_in[11], d_in[12], d_in[13], d_in[14],
                       d_in[15], d_in[16], d_in[17], d_in[18]);
    void* outp = d_out;
    const int* cseq = (const int*)d_in[1];
    const int* clen = (const int*)d_in[2];
    void* args[] = { (void*)&outp, (void*)&cseq, (void*)&clen };
    hipLaunchCooperativeKernel((void*)k_persist, dim3(120), dim3(512), args, 0, stream);
}

// Round 8
// 42328.027 us; speedup vs baseline: 2.2167x; 1.1951x over previous
//
#include <hip/hip_runtime.h>
#include <hip/hip_bf16.h>

#define NB 64
#define NT 600
#define NTC 50
#define NH 400
#define NKATT 10
#define NALPHA 60
#define NOUT 121

typedef unsigned short u16;
typedef _Float16 f16x2 __attribute__((ext_vector_type(2)));
typedef _Float16 f16x4 __attribute__((ext_vector_type(4)));
typedef _Float16 f16x8 __attribute__((ext_vector_type(8)));

#if defined(__has_builtin)
#if __has_builtin(__builtin_amdgcn_fdot2)
#define FDOT2(a,b,c) __builtin_amdgcn_fdot2((a),(b),(c),false)
#endif
#endif
#ifndef FDOT2
#define FDOT2(a,b,c) ((c) + (float)(a)[0]*(float)(b)[0] + (float)(a)[1]*(float)(b)[1])
#endif

// Padded fused-K sizes (pairs): K1=512->256, K2=896->448, K3=1280->640. Rows padded 1600->1664.
#define ROWSP 1664
#define GRPB 15            // blocks per batch-group barrier: 13 LSTM + 2 head

// state layout (floats)
#define H1OFF 0            // [2][NB][NH] ping-pong
#define H2OFF 51200
#define H3OFF 102400
#define C1OFF 153600
#define C2OFF 179200
#define C3OFF 204800
#define KPOFF 230400       // [2][NB][NKATT]
#define WINOFF 231680      // [NB][NALPHA]
#define ST_FLOATS 235520

// smem layout: [0,25600) = LDS-resident W_att (f16x2[200*32], persistent);
// [25600, 25600+25088) = per-phase region.
#define SMEM_P 25600
#define SMEM_TOTAL 50688

__device__ __align__(16) f16x2 g_WT1[256 * ROWSP];
__device__ __align__(16) f16x2 g_WT2[448 * ROWSP];
__device__ __align__(16) f16x2 g_WT3[640 * ROWSP];
__device__ __align__(16) f16x2 g_WG8[150 * 128 * 4];  // [k8][r][j] f16x2 pairs, 16B/(k8,r)
__device__ __align__(16) f16x2 g_WattP[200 * 32];     // [k2][r] f16 pairs
__device__ __align__(16) float g_fb1[ROWSP], g_fb2[ROWSP], g_fb3[ROWSP];
__device__ float g_batt[30], g_bgmm[121];
__device__ __align__(16) float g_inp[115200];
__device__ float g_state[ST_FLOATS];
__device__ unsigned int g_barcnt[8 * 32];   // one cacheline per batch-group
__device__ int   g_isf32;

__device__ __forceinline__ float bf2f(u16 v) {
    union { unsigned int u; float f; } t; t.u = ((unsigned int)v) << 16; return t.f;
}
__device__ __forceinline__ u16 f2bf(float f) {
    union { float ff; unsigned int u; } t; t.ff = f;
    unsigned int lsb = (t.u >> 16) & 1u;
    t.u += 0x7fffu + lsb;
    return (u16)(t.u >> 16);
}
__device__ __forceinline__ float sigm(float x) { return 1.f / (1.f + expf(-x)); }
__device__ __forceinline__ f16x2 packpair(float a, float b) {
    f16x2 r; r[0] = (_Float16)a; r[1] = (_Float16)b; return r;
}

// ---- agent-scope (cross-XCD coherent, LLC-direct) state accessors ----
__device__ __forceinline__ float ld_agent(const float* p) {
    return __hip_atomic_load(p, __ATOMIC_RELAXED, __HIP_MEMORY_SCOPE_AGENT);
}
__device__ __forceinline__ void st_agent(float* p, float v) {
    __hip_atomic_store(p, v, __ATOMIC_RELAXED, __HIP_MEMORY_SCOPE_AGENT);
}
__device__ __forceinline__ float2 ld2_agent(const float* p) {
    unsigned long long u = __hip_atomic_load((const unsigned long long*)p,
                                             __ATOMIC_RELAXED, __HIP_MEMORY_SCOPE_AGENT);
    union { unsigned long long u; float2 f; } t; t.u = u; return t.f;
}

// Split barrier: arrive (syncthreads drains vmcnt; tid0 bumps LLC counter),
// wait (tid0 spins; syncthreads releases). Between arrive and wait: stage OLD data only.
__device__ __forceinline__ void bar_arrive(int bg, unsigned* bars) {
    __syncthreads();
    ++(*bars);
    if (threadIdx.x == 0)
        __hip_atomic_fetch_add(&g_barcnt[bg * 32], 1u, __ATOMIC_RELAXED, __HIP_MEMORY_SCOPE_AGENT);
}
__device__ __forceinline__ void bar_wait(int bg, unsigned bars) {
    if (threadIdx.x == 0) {
        unsigned tgt = (unsigned)GRPB * bars;
        while (__hip_atomic_load(&g_barcnt[bg * 32], __ATOMIC_RELAXED, __HIP_MEMORY_SCOPE_AGENT) < tgt)
            __builtin_amdgcn_s_sleep(1);
    }
    __syncthreads();
}

__global__ void k_detect(const void* whh1) {
    if (threadIdx.x == 0 && blockIdx.x == 0) {
        const u16* p = (const u16*)whh1;
        int f32 = 0;
        for (int k = 0; k < 256; ++k) {
            float v = bf2f(p[2 * k]);
            if (!(fabsf(v) < 1e3f)) f32 = 1;
        }
        g_isf32 = f32;
    }
}

// Build fused/transposed/permuted f16 weights + biases; canonicalize inputs; zero state.
__global__ void k_convert(const void* inp,
                          const void* wih1, const void* bih1, const void* whh1, const void* bhh1,
                          const void* wih2, const void* bih2, const void* whh2, const void* bhh2,
                          const void* wih3, const void* bih3, const void* whh3, const void* bhh3,
                          const void* watt, const void* batt, const void* wgmm, const void* bgmm)
{
    const int gt = blockIdx.x * blockDim.x + threadIdx.x;
    const int gs = gridDim.x * blockDim.x;
    const int f32 = g_isf32;
    auto ld = [f32](const void* p, int i) -> float {
        return f32 ? ((const float*)p)[i] : bf2f(((const u16*)p)[i]);
    };
    auto w1col = [&](int kf, int row) -> float {
        if (kf < 400) return ld(whh1, row * 400 + kf);
        if (kf < 460) return ld(wih1, row * 63 + (kf - 400));
        if (kf < 463) return ld(wih1, row * 63 + 60 + (kf - 460));
        return 0.f;
    };
    auto w2col = [&](int kf, int row) -> float {
        if (kf < 400) return ld(wih2, row * 463 + 3 + kf);
        if (kf < 800) return ld(whh2, row * 400 + (kf - 400));
        if (kf < 860) return ld(wih2, row * 463 + 403 + (kf - 800));
        if (kf < 863) return ld(wih2, row * 463 + (kf - 860));
        return 0.f;
    };
    auto w3col = [&](int kf, int row) -> float {
        if (kf < 400)  return ld(wih3, row * 863 + 3 + kf);
        if (kf < 800)  return ld(wih3, row * 863 + 403 + (kf - 400));
        if (kf < 1200) return ld(whh3, row * 400 + (kf - 800));
        if (kf < 1260) return ld(wih3, row * 863 + 803 + (kf - 1200));
        if (kf < 1263) return ld(wih3, row * 863 + (kf - 1260));
        return 0.f;
    };
    for (int i = gt; i < 256 * ROWSP; i += gs) {
        int k2 = i / ROWSP, rp = i % ROWSP;
        int j = rp >> 2, g = rp & 3;
        float a = 0.f, b = 0.f;
        if (j < 400) { int row = g * 400 + j; a = w1col(2 * k2, row); b = w1col(2 * k2 + 1, row); }
        g_WT1[i] = packpair(a, b);
    }
    for (int i = gt; i < 448 * ROWSP; i += gs) {
        int k2 = i / ROWSP, rp = i % ROWSP;
        int j = rp >> 2, g = rp & 3;
        float a = 0.f, b = 0.f;
        if (j < 400) { int row = g * 400 + j; a = w2col(2 * k2, row); b = w2col(2 * k2 + 1, row); }
        g_WT2[i] = packpair(a, b);
    }
    for (int i = gt; i < 640 * ROWSP; i += gs) {
        int k2 = i / ROWSP, rp = i % ROWSP;
        int j = rp >> 2, g = rp & 3;
        float a = 0.f, b = 0.f;
        if (j < 400) { int row = g * 400 + j; a = w3col(2 * k2, row); b = w3col(2 * k2 + 1, row); }
        g_WT3[i] = packpair(a, b);
    }
    for (int i = gt; i < ROWSP; i += gs) {
        int j = i >> 2, g = i & 3;
        float b1 = 0.f, b2 = 0.f, b3 = 0.f;
        if (j < 400) {
            int row = g * 400 + j;
            b1 = ld(bih1, row) + ld(bhh1, row);
            b2 = ld(bih2, row) + ld(bhh2, row);
            b3 = ld(bih3, row) + ld(bhh3, row);
        }
        g_fb1[i] = b1; g_fb2[i] = b2; g_fb3[i] = b3;
    }
    for (int i = gt; i < 200 * 32; i += gs) {        // W_att f16 pairs [k2][r]
        int k2 = i / 32, r = i % 32;
        float a = 0.f, b = 0.f;
        if (r < 30) { a = ld(watt, r * 400 + 2 * k2); b = ld(watt, r * 400 + 2 * k2 + 1); }
        g_WattP[i] = packpair(a, b);
    }
    for (int i = gt; i < 150 * 128 * 4; i += gs) {   // W_gmm f16x8-coalesced [k8][r][j]
        int k8 = i >> 9, rem = i & 511, r = rem >> 2, j = rem & 3;
        int kp = k8 * 4 + j;
        float a = 0.f, b = 0.f;
        if (r < 121) { a = ld(wgmm, r * 1200 + 2 * kp); b = ld(wgmm, r * 1200 + 2 * kp + 1); }
        g_WG8[i] = packpair(a, b);
    }
    for (int i = gt; i < 30; i += gs)  g_batt[i] = ld(batt, i);
    for (int i = gt; i < 121; i += gs) g_bgmm[i] = ld(bgmm, i);
    for (int i = gt; i < 115200; i += gs) g_inp[i] = ld(inp, i);
    for (int i = gt; i < ST_FLOATS; i += gs) g_state[i] = 0.f;
    for (int i = gt; i < 8 * 32; i += gs) g_barcnt[i] = 0u;
}

// LSTM core: 8 waves split K in k4-groups; lane = 2 rowpairs x 8 batches.
template<int KP2>
__device__ __forceinline__ void lstm_core(const f16x2* __restrict__ WT, const float* __restrict__ fb,
                                          float* __restrict__ cst, float* __restrict__ hdst,
                                          const f16x2* inb, float* accS, int rg, int bg, int tid)
{
    const int wv = tid >> 6, lane = tid & 63;
    const int ck4 = KP2 >> 5;
    const int k40 = wv * ck4;
    const int rbase = rg * 128 + lane * 2;
    float acc[2][8];
    #pragma unroll
    for (int r = 0; r < 2; ++r)
        #pragma unroll
        for (int b = 0; b < 8; ++b) acc[r][b] = 0.f;
    const f16x2* wp = WT + (size_t)(k40 * 4) * ROWSP + rbase;
    #pragma unroll 2
    for (int k4 = 0; k4 < ck4; ++k4) {
        f16x2 wa[4], wb[4];
        #pragma unroll
        for (int j = 0; j < 4; ++j) {
            union { f16x4 v; f16x2 p[2]; } u;
            u.v = *(const f16x4*)(wp + (size_t)j * ROWSP);
            wa[j] = u.p[0]; wb[j] = u.p[1];
        }
        #pragma unroll
        for (int b = 0; b < 8; ++b) {
            union { f16x8 v; f16x2 p[4]; } h;
            h.v = *(const f16x8*)(inb + b * KP2 + (k40 + k4) * 4);
            #pragma unroll
            for (int j = 0; j < 4; ++j) {
                acc[0][b] = FDOT2(wa[j], h.p[j], acc[0][b]);
                acc[1][b] = FDOT2(wb[j], h.p[j], acc[1][b]);
            }
        }
        wp += 4 * ROWSP;
    }
    #pragma unroll
    for (int r = 0; r < 2; ++r)
        #pragma unroll
        for (int b = 0; b < 8; ++b)
            atomicAdd(&accS[(lane * 2 + r) * 9 + b], acc[r][b]);
    __syncthreads();
    if (tid < 256) {
        int bl = tid >> 5, jj = tid & 31;
        int j = rg * 32 + jj;
        if (j < 400) {
            int rl = jj * 4;
            float gi = accS[(rl + 0) * 9 + bl] + fb[rg * 128 + rl + 0];
            float gf = accS[(rl + 1) * 9 + bl] + fb[rg * 128 + rl + 1];
            float gg = accS[(rl + 2) * 9 + bl] + fb[rg * 128 + rl + 2];
            float go = accS[(rl + 3) * 9 + bl] + fb[rg * 128 + rl + 3];
            int b = bg * 8 + bl;
            float c = cst[b * 400 + j];               // owner-exclusive: plain
            float cn = sigm(gf) * c + sigm(gi) * tanhf(gg);
            cst[b * 400 + j] = cn;
            st_agent(&hdst[b * 400 + j], sigm(go) * tanhf(cn));  // cross-block: LLC
        }
    }
}

// GMM output head: 4 batches per block, 16B-coalesced f16x8 weights, 4 split acc chains.
__device__ void out_head(void* out, int tOut, int obid, int tid, char* smem)
{
    f16x2* zb = (f16x2*)(smem + SMEM_P);          // 9600
    float* zv = (float*)(smem + SMEM_P + 9600);   // 1936
    const int pp = tOut & 1;
    const float* h1 = g_state + H1OFF + pp * (NB * NH);
    const float* h2 = g_state + H2OFF + pp * (NB * NH);
    const float* h3 = g_state + H3OFF + pp * (NB * NH);
    for (int i = tid; i < 4 * 600; i += 512) {
        int bq = i / 600, p = i % 600; int b = obid * 4 + bq;
        int kf = 2 * p;
        const float* src = (kf < 400) ? (h1 + b * 400 + kf)
                         : (kf < 800) ? (h2 + b * 400 + (kf - 400))
                                      : (h3 + b * 400 + (kf - 800));
        float2 hv = ld2_agent(src);
        zb[bq * 600 + p] = packpair(hv.x, hv.y);
    }
    __syncthreads();
    {
        int bq = tid >> 7, r = tid & 127;
        float ac0 = (r < 121) ? g_bgmm[r] : 0.f, ac1 = 0.f, ac2 = 0.f, ac3 = 0.f;
        const f16x8* zp = (const f16x8*)(zb + bq * 600);   // 150 x 16B
        #pragma unroll 4
        for (int k8 = 0; k8 < 150; ++k8) {
            union { f16x8 v; f16x2 p[4]; } w, z;
            w.v = *(const f16x8*)&g_WG8[(k8 * 128 + r) * 4];
            z.v = zp[k8];
            ac0 = FDOT2(w.p[0], z.p[0], ac0);
            ac1 = FDOT2(w.p[1], z.p[1], ac1);
            ac2 = FDOT2(w.p[2], z.p[2], ac2);
            ac3 = FDOT2(w.p[3], z.p[3], ac3);
        }
        if (r < 121) zv[bq * 121 + r] = (ac0 + ac1) + (ac2 + ac3);
    }
    __syncthreads();
    if (tid < 484) {
        int bl = tid / 121, jo = tid - bl * 121;
        const float* z = zv + bl * 121;
        float val;
        if (jo < 20) {
            float m = -1e30f;
            for (int i = 0; i < 20; ++i) m = fmaxf(m, z[1 + i]);
            float s = 0.f;
            for (int i = 0; i < 20; ++i) s += expf(z[1 + i] - m);
            val = expf(z[1 + jo] - m) / s;
        } else if (jo < 60)  val = z[jo + 1];
        else if (jo < 100)   val = expf(z[jo + 1]);
        else if (jo < 120)   val = tanhf(z[jo + 1]);
        else                 val = 1.f / (1.f + expf(-z[0]));
        int idx = ((obid * 4 + bl) * NT + tOut) * NOUT + jo;
        if (g_isf32) ((float*)out)[idx] = val;
        else         ((u16*)out)[idx]  = f2bf(val);
    }
    __syncthreads();
}

// Phase A: LSTM1, inputs h1[prev]+win(t-1)+x — all published >=1 barrier ago.
__device__ void phaseA_lstm1(int t, int cur, int prev, int rg, int bg, int tid, char* smem)
{
    f16x2* inb = (f16x2*)(smem + SMEM_P);             // 8192
    float* accS = (float*)(smem + SMEM_P + 8192);     // 4608
    const float* h1p = g_state + H1OFF + prev * (NB * NH);
    for (int i = tid; i < 8 * 256; i += 512) {
        int bl = i >> 8, p = i & 255; int b = bg * 8 + bl;
        float a = 0.f, v = 0.f;
        if (p < 200)      { float2 hv = ld2_agent(h1p + b * 400 + 2 * p); a = hv.x; v = hv.y; }
        else if (p < 230) { int q = p - 200;
                            float2 wv = ld2_agent(g_state + WINOFF + b * 60 + 2 * q);
                            a = wv.x; v = wv.y; }
        else if (p == 230){ a = g_inp[(b * NT + t) * 3 + 0]; v = g_inp[(b * NT + t) * 3 + 1]; }
        else if (p == 231){ a = g_inp[(b * NT + t) * 3 + 2]; }
        inb[bl * 256 + p] = packpair(a, v);
    }
    for (int i = tid; i < 1152; i += 512) accS[i] = 0.f;
    __syncthreads();
    lstm_core<256>(g_WT1, g_fb1, g_state + C1OFF, g_state + H1OFF + cur * (NB * NH),
                   inb, accS, rg, bg, tid);
}

// Phase B early (between barA.arrive and barA.wait): stage OLD data only.
__device__ void pB_early(const int* __restrict__ cseq, const int* __restrict__ clen,
                         int t, int prev, int bg, int tid, char* smem)
{
    f16x2* inb  = (f16x2*)(smem + SMEM_P);
    float* accS = (float*)(smem + SMEM_P + 14336);
    float* kap  = (float*)(smem + SMEM_P + 21504);
    int*   chs  = (int*)  (smem + SMEM_P + 21824);
    int*   len  = (int*)  (smem + SMEM_P + 23424);
    const float* h2p = g_state + H2OFF + prev * (NB * NH);
    for (int i = tid; i < 8 * 248; i += 512) {
        int bl = i / 248, p = 200 + i % 248; int b = bg * 8 + bl;
        float a = 0.f, v = 0.f;
        if (p < 400)      { int q = p - 200; float2 hv = ld2_agent(h2p + b * 400 + 2 * q); a = hv.x; v = hv.y; }
        else if (p == 430){ a = g_inp[(b * NT + t) * 3 + 0]; v = g_inp[(b * NT + t) * 3 + 1]; }
        else if (p == 431){ a = g_inp[(b * NT + t) * 3 + 2]; }
        if (p < 400 || p >= 430)                       // [400,430) = window, filled in late
            inb[bl * 448 + p] = packpair(a, v);
    }
    for (int i = tid; i < 1152; i += 512) accS[i] = 0.f;
    if (tid < 80) { int bl = tid / 10, k = tid % 10;
        kap[tid] = ld_agent(g_state + KPOFF + prev * (NB * NKATT) + (bg * 8 + bl) * 10 + k); }
    else if (tid >= 80 && tid < 480) { int i = tid - 80; int bl = i / 50, u = i % 50;
        chs[bl * 50 + u] = cseq[(bg * 8 + bl) * NTC + u]; }
    else if (tid >= 480 && tid < 488) len[tid - 480] = clen[bg * 8 + (tid - 480)];
}

// Phase B late (after barA.wait): h1 staging + LDS-resident attention + LSTM2.
__device__ void pB_late(int t, int cur, int rg, int bg, int tid, char* smem)
{
    f16x2* wattL = (f16x2*)smem;                      // persistent [200*32]
    f16x2* inb  = (f16x2*)(smem + SMEM_P);
    float* accS = (float*)(smem + SMEM_P + 14336);
    float* ab   = (float*)(smem + SMEM_P + 18944);
    float* phi  = (float*)(smem + SMEM_P + 19904);
    float* kap  = (float*)(smem + SMEM_P + 21504);
    int*   chs  = (int*)  (smem + SMEM_P + 21824);
    int*   len  = (int*)  (smem + SMEM_P + 23424);
    const float* h1 = g_state + H1OFF + cur * (NB * NH);
    for (int i = tid; i < 8 * 200; i += 512) {
        int bl = i / 200, p = i % 200; int b = bg * 8 + bl;
        float2 hv = ld2_agent(h1 + b * 400 + 2 * p);
        inb[bl * 448 + p] = packpair(hv.x, hv.y);
    }
    __syncthreads();
    if (tid < 240) {                       // p = exp(h1 @ W_att.T + b_att), all-LDS dot2
        int bl = tid / 30, rr = tid % 30;
        float a0 = g_batt[rr], a1 = 0.f;
        const f16x2* hp = inb + bl * 448;
        #pragma unroll 4
        for (int k2 = 0; k2 < 200; k2 += 2) {
            a0 = FDOT2(wattL[(k2 + 0) * 32 + rr], hp[k2 + 0], a0);
            a1 = FDOT2(wattL[(k2 + 1) * 32 + rr], hp[k2 + 1], a1);
        }
        ab[bl * 30 + rr] = expf(a0 + a1);
    }
    __syncthreads();
    if (tid < 400) {                       // phi (length-masked)
        int bl = tid / 50, u = tid % 50;
        float ph = 0.f;
        if (u < len[bl]) {
            float uf = (float)u;
            for (int k = 0; k < 10; ++k) {
                float kn = kap[bl * 10 + k] + ab[bl * 30 + 20 + k];
                float d = kn - uf;
                ph += ab[bl * 30 + k] * expf(-ab[bl * 30 + 10 + k] * d * d);
            }
        }
        phi[bl * 50 + u] = ph;
    } else if (tid >= 400 && tid < 480 && rg == 0) {   // kappa writer
        int i = tid - 400; int bl = i / 10, k = i % 10;
        st_agent(g_state + KPOFF + cur * (NB * NKATT) + (bg * 8 + bl) * 10 + k,
                 kap[bl * 10 + k] + ab[bl * 30 + 20 + k]);
    }
    __syncthreads();
    if (tid < 240) {                       // window pairs -> inb + g_state
        int bl = tid / 30, q = tid % 30;
        int a0 = 2 * q, a1 = 2 * q + 1;
        float w0 = 0.f, w1 = 0.f;
        for (int u = 0; u < NTC; ++u) {
            float pv = phi[bl * 50 + u]; int cc = chs[bl * 50 + u];
            if (cc == a0) w0 += pv;
            if (cc == a1) w1 += pv;
        }
        inb[bl * 448 + 400 + q] = packpair(w0, w1);
        if (rg == 0) { int b = bg * 8 + bl;
            st_agent(g_state + WINOFF + b * 60 + a0, w0);
            st_agent(g_state + WINOFF + b * 60 + a1, w1); }
    }
    __syncthreads();
    lstm_core<448>(g_WT2, g_fb2, g_state + C2OFF, g_state + H2OFF + cur * (NB * NH),
                   inb, accS, rg, bg, tid);
}

// Phase C early (between barB.arrive and barB.wait): h1 (ready since barA), h3p, x.
__device__ void pC_early(int t, int cur, int prev, int bg, int tid, char* smem)
{
    f16x2* inb  = (f16x2*)(smem + SMEM_P);
    float* accS = (float*)(smem + SMEM_P + 20480);
    const float* h1  = g_state + H1OFF + cur  * (NB * NH);
    const float* h3p = g_state + H3OFF + prev * (NB * NH);
    for (int i = tid; i < 8 * 440; i += 512) {
        int bl = i / 440, j = i % 440; int b = bg * 8 + bl;
        int p; float a = 0.f, v = 0.f; bool wr = true;
        if (j < 200) { p = j; float2 hv = ld2_agent(h1 + b * 400 + 2 * p); a = hv.x; v = hv.y; }
        else {
            p = j + 200;                                    // p in [400,640)
            if (p < 600)      { int q = p - 400; float2 hv = ld2_agent(h3p + b * 400 + 2 * q); a = hv.x; v = hv.y; }
            else if (p == 630){ a = g_inp[(b * NT + t) * 3 + 0]; v = g_inp[(b * NT + t) * 3 + 1]; }
            else if (p == 631){ a = g_inp[(b * NT + t) * 3 + 2]; }
            else if (p < 630) wr = false;                   // [600,630) = win, staged late
        }
        if (wr) inb[bl * 640 + p] = packpair(a, v);
    }
    for (int i = tid; i < 1152; i += 512) accS[i] = 0.f;
}

// Phase C late (after barB.wait): h2 + win staging, then LSTM3.
__device__ void pC_late(int cur, int rg, int bg, int tid, char* smem)
{
    f16x2* inb  = (f16x2*)(smem + SMEM_P);
    float* accS = (float*)(smem + SMEM_P + 20480);
    const float* h2 = g_state + H2OFF + cur * (NB * NH);
    for (int i = tid; i < 8 * 230; i += 512) {
        int bl = i / 230, j = i % 230; int b = bg * 8 + bl;
        float a, v; int p;
        if (j < 200) { p = 200 + j; int q = j;
                       float2 hv = ld2_agent(h2 + b * 400 + 2 * q); a = hv.x; v = hv.y; }
        else         { p = 600 + (j - 200); int q = j - 200;
                       float2 wv = ld2_agent(g_state + WINOFF + b * 60 + 2 * q); a = wv.x; v = wv.y; }
        inb[bl * 640 + p] = packpair(a, v);
    }
    __syncthreads();
    lstm_core<640>(g_WT3, g_fb3, g_state + C3OFF, g_state + H3OFF + cur * (NB * NH),
                   inb, accS, rg, bg, tid);
    __syncthreads();   // LDS reuse guard before next phase A
}

// Persistent kernel, XCD-affinity swizzle (XCD = bid%8). 2 barriers/step + 1 final.
__global__ __launch_bounds__(512) void k_persist(void* out,
                                                 const int* __restrict__ cseq,
                                                 const int* __restrict__ clen)
{
    __shared__ __align__(16) char smem[SMEM_TOTAL];
    const int tid = threadIdx.x;
    const int bid = blockIdx.x;
    const int x = bid & 7, s = bid >> 3;
    bool isL; int rg = 0, bg, obid = 0;
    if (s < 8)       { isL = true;  rg = x; bg = s; }
    else if (s < 13) { isL = true;  int q = 5 * x + (s - 8); rg = 8 + (q >> 3); bg = q & 7; }
    else             { isL = false; obid = 2 * x + (s - 13); bg = x; }
    {   // one-time: W_att into persistent LDS region
        f16x2* wattL = (f16x2*)smem;
        for (int i = tid; i < 200 * 32; i += 512) wattL[i] = g_WattP[i];
    }
    __syncthreads();
    unsigned bars = 0;
    for (int t = 0; t < NT; ++t) {
        const int cur = t & 1, prev = cur ^ 1;
        if (isL) phaseA_lstm1(t, cur, prev, rg, bg, tid, smem);
        bar_arrive(bg, &bars);                      // barA: publishes h1(t)
        if (isL) pB_early(cseq, clen, t, prev, bg, tid, smem);
        bar_wait(bg, bars);
        if (isL)        pB_late(t, cur, rg, bg, tid, smem);
        else if (t > 0) out_head(out, t - 1, obid, tid, smem);   // h3(t-1) gated by barA
        bar_arrive(bg, &bars);                      // barB: publishes h2(t), win(t)
        if (isL) pC_early(t, cur, prev, bg, tid, smem);
        bar_wait(bg, bars);
        if (isL) pC_late(cur, rg, bg, tid, smem);
        // no barrier after C: next-step A reads only h1/win (already gated);
        // h3 consumers (C(t+1), out_head(t)) are gated by the next barriers.
    }
    bar_arrive(bg, &bars);                          // final: publish h3(NT-1)
    bar_wait(bg, bars);
    if (!isL) out_head(out, NT - 1, obid, tid, smem);
}

extern "C" void kernel_launch(void* const* d_in, const int* in_sizes, int n_in,
                              void* d_out, int out_size, void* d_ws, size_t ws_size,
                              hipStream_t stream)
{
    hipLaunchKernelGGL(k_detect, dim3(1), dim3(64), 0, stream, d_in[5]);  // W_hh1
    hipLaunchKernelGGL(k_convert, dim3(2048), dim3(256), 0, stream,
                       d_in[0],
                       d_in[3], d_in[4], d_in[5], d_in[6],
                       d_in[7], d_in[8], d_in[9], d_in[10],
                       d_in[11], d_in[12], d_in[13], d_in[14],
                       d_in[15], d_in[16], d_in[17], d_in[18]);
    void* outp = d_out;
    const int* cseq = (const int*)d_in[1];
    const int* clen = (const int*)d_in[2];
    void* args[] = { (void*)&outp, (void*)&cseq, (void*)&clen };
    hipLaunchCooperativeKernel((void*)k_persist, dim3(120), dim3(512), args, 0, stream);
}